// Round 6
// baseline (1537.646 us; speedup 1.0000x reference)
//
#include <hip/hip_runtime.h>
#include <hip/hip_bf16.h>
#include <math.h>

// DAGNN r6: (A) CSR build via two-level bucket sort (passA hist + passB pair
// scatter into (sub,bucket) windows + passC per-bucket LDS-cursor scatter) —
// kills the 16x random-write amplification of the old fill_csr.
// (B) MLP: pre-transposed bf16 weights, GEMM1 BN=256, CH=50000.
// spmm/hop0 unchanged (r3 form, bf16 state).

#define WAVE 64

__device__ inline float bf2f(unsigned short u) {
    union { unsigned int i; float f; } v; v.i = ((unsigned int)u) << 16; return v.f;
}
__device__ inline unsigned short f2bf(float f) {
    __hip_bfloat16 b = __float2bfloat16(f);
    union { __hip_bfloat16 b; unsigned short u; } v; v.b = b; return v.u;
}

typedef __attribute__((ext_vector_type(8))) short bf16x8;
typedef __attribute__((ext_vector_type(16))) float f32x16;

// ---- edge dtype detection: stride 1 (int32) or 2 (int64 low words) ----
__global__ void detect_kernel(const unsigned* __restrict__ e, int* __restrict__ sflag) {
    __shared__ int any;
    if (threadIdx.x == 0) any = 0;
    __syncthreads();
    unsigned nz = 0;
    int t = threadIdx.x;
    for (int i = 0; i < 8; ++i) nz |= e[(size_t)(t * 8 + i) * 2 + 1];
    if (nz) atomicOr(&any, 1);
    __syncthreads();
    if (t == 0) *sflag = any ? 1 : 2;
}

__global__ void init_int_kernel(int* __restrict__ p, int n) {
    int i = blockIdx.x * blockDim.x + threadIdx.x;
    if (i < n) p[i] = 0;
}

// ---- passA: per-node degree counts + per-(sub,bucket) histogram ----
__global__ void passA_kernel(const int* __restrict__ eidx, const int* __restrict__ sflag,
                             int* __restrict__ cnt, int* __restrict__ hist8,
                             int E, int NB, int EPB) {
    __shared__ int lh[512];
    int t = threadIdx.x;
    for (int i = t; i < NB; i += 256) lh[i] = 0;
    __syncthreads();
    int s = *sflag;
    int base = blockIdx.x * EPB;
    int end = base + EPB; if (end > E) end = E;
    for (int e = base + t; e < end; e += 256) {
        int c = eidx[(size_t)s * (size_t)(E + e)];
        atomicAdd(&cnt[c], 1);
        atomicAdd(&lh[c >> 8], 1);
    }
    __syncthreads();
    int sub = blockIdx.x & 7;
    for (int i = t; i < NB; i += 256)
        if (lh[i]) atomicAdd(&hist8[sub * NB + i], lh[i]);
}

__global__ void dinv_kernel(const int* __restrict__ cnt, float* __restrict__ dinv, int n) {
    int i = blockIdx.x * blockDim.x + threadIdx.x;
    if (i < n) dinv[i] = rsqrtf((float)(cnt[i] + 1));  // self-loop adds 1
}

// ---- exclusive scan of cnt -> offs ----
__global__ void scan1_kernel(const int* __restrict__ cnt, int* __restrict__ out,
                             int* __restrict__ bsums, int n) {
    __shared__ int s[256];
    int t = threadIdx.x;
    int idx = blockIdx.x * 1024 + t * 4;
    int x0 = (idx + 0 < n) ? cnt[idx + 0] : 0;
    int x1 = (idx + 1 < n) ? cnt[idx + 1] : 0;
    int x2 = (idx + 2 < n) ? cnt[idx + 2] : 0;
    int x3 = (idx + 3 < n) ? cnt[idx + 3] : 0;
    int lsum = x0 + x1 + x2 + x3;
    s[t] = lsum;
    __syncthreads();
    for (int o = 1; o < 256; o <<= 1) {
        int v = (t >= o) ? s[t - o] : 0;
        __syncthreads();
        if (t >= o) s[t] += v;
        __syncthreads();
    }
    int excl = s[t] - lsum;
    if (idx + 0 < n) out[idx + 0] = excl;
    if (idx + 1 < n) out[idx + 1] = excl + x0;
    if (idx + 2 < n) out[idx + 2] = excl + x0 + x1;
    if (idx + 3 < n) out[idx + 3] = excl + x0 + x1 + x2;
    if (t == 255) bsums[blockIdx.x] = s[255];
}

__global__ void scan2_kernel(int* __restrict__ bsums, int nb) {
    __shared__ int s[256];
    int t = threadIdx.x;
    int v = (t < nb) ? bsums[t] : 0;
    s[t] = v;
    __syncthreads();
    for (int o = 1; o < 256; o <<= 1) {
        int x = (t >= o) ? s[t - o] : 0;
        __syncthreads();
        if (t >= o) s[t] += x;
        __syncthreads();
    }
    if (t < nb) bsums[t] = s[t] - v;
}

__global__ void scan3_kernel(int* __restrict__ offs, const int* __restrict__ bsums,
                             int n, int total) {
    int t = threadIdx.x;
    int idx = blockIdx.x * 1024 + t * 4;
    int add = bsums[blockIdx.x];
    #pragma unroll
    for (int i = 0; i < 4; ++i)
        if (idx + i < n) offs[idx + i] += add;
    if (blockIdx.x == 0 && t == 0) offs[n] = total;
}

// ---- scan of hist8[M] -> pbase (exclusive), pcur copy; pbase[M] = total ----
__global__ void pscan_kernel(const int* __restrict__ hist8, int* __restrict__ pbase,
                             int* __restrict__ pcur, int M, int total) {
    __shared__ int part[256];
    int t = threadIdx.x;
    const int CHK = 13;
    int vals[CHK];
    int c0 = t * CHK;
    int run = 0;
    #pragma unroll
    for (int j = 0; j < CHK; ++j) {
        int i = c0 + j;
        int v = (i < M) ? hist8[i] : 0;
        vals[j] = run;
        run += v;
    }
    part[t] = run;
    __syncthreads();
    for (int o = 1; o < 256; o <<= 1) {
        int v = (t >= o) ? part[t - o] : 0;
        __syncthreads();
        if (t >= o) part[t] += v;
        __syncthreads();
    }
    int excl = part[t] - run;
    #pragma unroll
    for (int j = 0; j < CHK; ++j) {
        int i = c0 + j;
        if (i < M) { int v = excl + vals[j]; pbase[i] = v; pcur[i] = v; }
    }
    if (t == 255) pbase[M] = total;
}

// ---- passB: scatter (r,c) pairs into (sub,bucket) windows ----
__global__ void passB_kernel(const int* __restrict__ eidx, const int* __restrict__ sflag,
                             int* __restrict__ pcur, int2* __restrict__ pairs,
                             int E, int NB, int EPB) {
    int t = threadIdx.x;
    int s = *sflag;
    int sub = blockIdx.x & 7;
    int base = blockIdx.x * EPB;
    int end = base + EPB; if (end > E) end = E;
    for (int e = base + t; e < end; e += 256) {
        int r = eidx[(size_t)s * (size_t)e];
        int c = eidx[(size_t)s * (size_t)(E + e)];
        int b = c >> 8;
        int pos = atomicAdd(&pcur[sub * NB + b], 1);
        pairs[pos] = make_int2(r, c);
    }
}

// ---- passC: per-bucket LDS cursors, scatter src into final CSR window ----
__global__ void passC_kernel(const int2* __restrict__ pairs, const int* __restrict__ pbase,
                             const int* __restrict__ offs, int* __restrict__ csr_src,
                             int N, int NB) {
    __shared__ int lcur[256];
    int b = blockIdx.x;
    int t = threadIdx.x;
    int node = b * 256 + t;
    if (node < N) lcur[t] = offs[node];
    __syncthreads();
    for (int sub = 0; sub < 8; ++sub) {
        int i = sub * NB + b;
        int w0 = pbase[i], w1 = pbase[i + 1];
        for (int idx = w0 + t; idx < w1; idx += 256) {
            int2 p = pairs[idx];
            int pos = atomicAdd(&lcur[p.y & 255], 1);
            csr_src[pos] = p.x;
        }
    }
}

// ---- weight convert+transpose: Wt[n][k] = bf16(W[k][n]) ----
__global__ void wconv_kernel(const float* __restrict__ W, unsigned short* __restrict__ Wt,
                             int K, int Nn) {
    int i = blockIdx.x * blockDim.x + threadIdx.x;
    if (i >= K * Nn) return;
    int n = i / K, k = i - n * K;
    Wt[(size_t)n * K + k] = f2bf(W[(size_t)k * Nn + n]);
}

// ---- GEMM1: A fp32 [M][256] x W1t bf16 [256][256] -> h1 bf16 [M][256], relu.
// BM=128, BN=256, BK=32, 256 thr (2x2 waves, wave tile 64x128). ----
__global__ __launch_bounds__(256) void gemm1_kernel(
        const float* __restrict__ A, const unsigned short* __restrict__ Bt,
        const float* __restrict__ bias, unsigned short* __restrict__ C, int M) {
    __shared__ unsigned short Asub[128][40];
    __shared__ unsigned short Bsub[256][40];
    int tid = threadIdx.x;
    int wave = tid >> 6, lane = tid & 63;
    int wm = wave >> 1, wn = wave & 1;
    int bm = blockIdx.x * 128;
    int half = lane >> 5, l31 = lane & 31;

    f32x16 acc[2][4] = {};

    for (int k0 = 0; k0 < 256; k0 += 32) {
        // A: 128x32 fp32 -> bf16
        #pragma unroll
        for (int i = 0; i < 4; ++i) {
            int f = i * 256 + tid;            // float4 slots
            int row = f >> 3, c4 = (f & 7) * 4;
            int grow = bm + row;
            float4 v = make_float4(0.f, 0.f, 0.f, 0.f);
            if (grow < M) v = *(const float4*)(A + (size_t)grow * 256 + k0 + c4);
            ushort4 uu;
            uu.x = f2bf(v.x); uu.y = f2bf(v.y); uu.z = f2bf(v.z); uu.w = f2bf(v.w);
            *(ushort4*)&Asub[row][c4] = uu;
        }
        // B: 256 rows(n) x 32(k) bf16, vectorized
        {
            const unsigned short* p = Bt + (size_t)tid * 256 + k0;
            uint4 u0 = *(const uint4*)(p);
            uint4 u1 = *(const uint4*)(p + 8);
            uint4 u2 = *(const uint4*)(p + 16);
            uint4 u3 = *(const uint4*)(p + 24);
            *(uint4*)&Bsub[tid][0]  = u0;
            *(uint4*)&Bsub[tid][8]  = u1;
            *(uint4*)&Bsub[tid][16] = u2;
            *(uint4*)&Bsub[tid][24] = u3;
        }
        __syncthreads();
        #pragma unroll
        for (int ks = 0; ks < 32; ks += 16) {
            bf16x8 a0 = *(bf16x8*)&Asub[wm * 64 + l31][ks + half * 8];
            bf16x8 a1 = *(bf16x8*)&Asub[wm * 64 + 32 + l31][ks + half * 8];
            #pragma unroll
            for (int j = 0; j < 4; ++j) {
                bf16x8 bf = *(bf16x8*)&Bsub[wn * 128 + j * 32 + l31][ks + half * 8];
                acc[0][j] = __builtin_amdgcn_mfma_f32_32x32x16_bf16(a0, bf, acc[0][j], 0, 0, 0);
                acc[1][j] = __builtin_amdgcn_mfma_f32_32x32x16_bf16(a1, bf, acc[1][j], 0, 0, 0);
            }
        }
        __syncthreads();
    }

    #pragma unroll
    for (int j = 0; j < 4; ++j) {
        int col = wn * 128 + j * 32 + l31;
        float bv = bias[col];
        #pragma unroll
        for (int mt = 0; mt < 2; ++mt) {
            #pragma unroll
            for (int reg = 0; reg < 16; ++reg) {
                int rowin = (reg & 3) + 8 * (reg >> 2) + 4 * half;
                int grow = bm + wm * 64 + mt * 32 + rowin;
                if (grow < M) {
                    float v = fmaxf(acc[mt][j][reg] + bv, 0.f);
                    C[(size_t)grow * 256 + col] = f2bf(v);
                }
            }
        }
    }
}

// ---- GEMM2: h1 bf16 [M][256] x W2t bf16 [64][256] -> hA fp32 [M][64].
// BM=128, BN=64, 256 thr (4 waves, wave tile 32x64). ----
__global__ __launch_bounds__(256) void gemm2_kernel(
        const unsigned short* __restrict__ A, const unsigned short* __restrict__ Bt,
        const float* __restrict__ bias, float* __restrict__ C, int M) {
    __shared__ unsigned short Asub[128][40];
    __shared__ unsigned short Bsub[64][40];
    int tid = threadIdx.x;
    int wave = tid >> 6, lane = tid & 63;
    int bm = blockIdx.x * 128;
    int half = lane >> 5, l31 = lane & 31;

    f32x16 acc[2] = {};

    for (int k0 = 0; k0 < 256; k0 += 32) {
        // A: 128x32 bf16 vectorized
        #pragma unroll
        for (int i = 0; i < 2; ++i) {
            int f = i * 256 + tid;            // ushort8 slots
            int row = f >> 2, c8 = (f & 3) * 8;
            int grow = bm + row;
            uint4 u = make_uint4(0, 0, 0, 0);
            if (grow < M) u = *(const uint4*)(A + (size_t)grow * 256 + k0 + c8);
            *(uint4*)&Asub[row][c8] = u;
        }
        // B: 64 rows(n) x 32(k)
        {
            int n = tid >> 2, k8 = (tid & 3) * 8;
            uint4 u = *(const uint4*)(Bt + (size_t)n * 256 + k0 + k8);
            *(uint4*)&Bsub[n][k8] = u;
        }
        __syncthreads();
        #pragma unroll
        for (int ks = 0; ks < 32; ks += 16) {
            bf16x8 a = *(bf16x8*)&Asub[wave * 32 + l31][ks + half * 8];
            #pragma unroll
            for (int j = 0; j < 2; ++j) {
                bf16x8 bf = *(bf16x8*)&Bsub[j * 32 + l31][ks + half * 8];
                acc[j] = __builtin_amdgcn_mfma_f32_32x32x16_bf16(a, bf, acc[j], 0, 0, 0);
            }
        }
        __syncthreads();
    }

    #pragma unroll
    for (int j = 0; j < 2; ++j) {
        int col = j * 32 + l31;
        float bv = bias[col];
        #pragma unroll
        for (int reg = 0; reg < 16; ++reg) {
            int rowin = (reg & 3) + 8 * (reg >> 2) + 4 * half;
            int grow = bm + wave * 32 + rowin;
            if (grow < M) C[(size_t)grow * 64 + col] = acc[j][reg] + bv;
        }
    }
}

// ---- hop 0: out = sigmoid(h.pw + pb)*h ; g0 = bf16(dinv*h) ----
__global__ void hop0_kernel(const float* __restrict__ h, const float* __restrict__ dinv,
                            const float* __restrict__ pw, const float* __restrict__ pb,
                            float* __restrict__ out, __hip_bfloat16* __restrict__ g, int n) {
    int wid = (blockIdx.x * blockDim.x + threadIdx.x) >> 6;
    int lane = threadIdx.x & 63;
    if (wid >= n) return;
    float v = h[(size_t)wid * 64 + lane];
    float d = v * pw[lane];
    #pragma unroll
    for (int o = 32; o > 0; o >>= 1) d += __shfl_xor(d, o, 64);
    float sg = 1.f / (1.f + __expf(-(d + pb[0])));
    out[(size_t)wid * 64 + lane] = sg * v;
    g[(size_t)wid * 64 + lane] = __float2bfloat16(dinv[wid] * v);
}

// ---- one hop (r3 form): wave per dest, uniform edge indices, bf16 gathers ----
__global__ void spmm_kernel(const int* __restrict__ offs, const int* __restrict__ src,
                            const float* __restrict__ dinv,
                            const __hip_bfloat16* __restrict__ gin,
                            __hip_bfloat16* __restrict__ gout,
                            float* __restrict__ out,
                            const float* __restrict__ pw, const float* __restrict__ pb,
                            int n) {
    int wid = (blockIdx.x * blockDim.x + threadIdx.x) >> 6;
    int lane = threadIdx.x & 63;
    if (wid >= n) return;
    int c = __builtin_amdgcn_readfirstlane(wid);
    int e = __builtin_amdgcn_readfirstlane(offs[c]);
    int eend = __builtin_amdgcn_readfirstlane(offs[c + 1]);
    float acc = 0.f;
    while (e < eend && (e & 3)) {
        acc += __bfloat162float(gin[(size_t)src[e] * 64 + lane]);
        ++e;
    }
    for (; e + 7 < eend; e += 8) {
        int4 sa = *(const int4*)(src + e);
        int4 sb = *(const int4*)(src + e + 4);
        float v0 = __bfloat162float(gin[(size_t)sa.x * 64 + lane]);
        float v1 = __bfloat162float(gin[(size_t)sa.y * 64 + lane]);
        float v2 = __bfloat162float(gin[(size_t)sa.z * 64 + lane]);
        float v3 = __bfloat162float(gin[(size_t)sa.w * 64 + lane]);
        float v4 = __bfloat162float(gin[(size_t)sb.x * 64 + lane]);
        float v5 = __bfloat162float(gin[(size_t)sb.y * 64 + lane]);
        float v6 = __bfloat162float(gin[(size_t)sb.z * 64 + lane]);
        float v7 = __bfloat162float(gin[(size_t)sb.w * 64 + lane]);
        acc += ((v0 + v1) + (v2 + v3)) + ((v4 + v5) + (v6 + v7));
    }
    for (; e + 3 < eend; e += 4) {
        int4 sa = *(const int4*)(src + e);
        float v0 = __bfloat162float(gin[(size_t)sa.x * 64 + lane]);
        float v1 = __bfloat162float(gin[(size_t)sa.y * 64 + lane]);
        float v2 = __bfloat162float(gin[(size_t)sa.z * 64 + lane]);
        float v3 = __bfloat162float(gin[(size_t)sa.w * 64 + lane]);
        acc += (v0 + v1) + (v2 + v3);
    }
    for (; e < eend; ++e) acc += __bfloat162float(gin[(size_t)src[e] * 64 + lane]);

    float dc = dinv[c];
    float h = dc * (acc + __bfloat162float(gin[(size_t)c * 64 + lane]));
    gout[(size_t)c * 64 + lane] = __float2bfloat16(dc * h);
    float d = h * pw[lane];
    #pragma unroll
    for (int o = 32; o > 0; o >>= 1) d += __shfl_xor(d, o, 64);
    float sg = 1.f / (1.f + __expf(-(d + pb[0])));
    out[(size_t)c * 64 + lane] += sg * h;
}

extern "C" void kernel_launch(void* const* d_in, const int* in_sizes, int n_in,
                              void* d_out, int out_size, void* d_ws, size_t ws_size,
                              hipStream_t stream) {
    const float* x  = (const float*)d_in[0];
    const int* eidx = (const int*)d_in[1];
    const float* W1 = (const float*)d_in[2];
    const float* b1 = (const float*)d_in[3];
    const float* W2 = (const float*)d_in[4];
    const float* b2 = (const float*)d_in[5];
    const float* pw = (const float*)d_in[6];
    const float* pb = (const float*)d_in[7];
    float* out = (float*)d_out;

    const int N = in_sizes[0] / 256;
    const int E = in_sizes[1] / 2;
    const int NB = (N + 255) >> 8;          // buckets of 256 dest nodes
    const int NBLOCKS = 1024;               // passA/passB grid (sub = blk&7)
    const int EPB = (E + NBLOCKS - 1) / NBLOCKS;
    const int M8 = 8 * NB;                  // hist8/pbase entries

    size_t woff = 0;
    auto alloc = [&](size_t bytes) -> void* {
        void* p = (char*)d_ws + woff;
        woff += (bytes + 255) & ~(size_t)255;
        return p;
    };
    int*   sflag   = (int*)alloc(4);
    int*   cnt     = (int*)alloc((size_t)N * 4);
    float* dinv    = (float*)alloc((size_t)N * 4);
    int*   offs    = (int*)alloc(((size_t)N + 1) * 4);
    int*   bsums   = (int*)alloc(256 * 4);
    int*   hist8   = (int*)alloc((size_t)M8 * 4);
    int*   pbase   = (int*)alloc(((size_t)M8 + 1) * 4);
    int*   pcur    = (int*)alloc((size_t)M8 * 4);
    int*   csr_src = (int*)alloc((size_t)E * 4);
    int2*  pairs   = (int2*)alloc((size_t)E * 8);
    unsigned short* W1t = (unsigned short*)alloc((size_t)256 * 256 * 2);
    unsigned short* W2t = (unsigned short*)alloc((size_t)64 * 256 * 2);
    const int CH = 50000;
    unsigned short* h1 = (unsigned short*)alloc((size_t)CH * 256 * 2);
    float* hA = (float*)alloc((size_t)N * 64 * 4);
    __hip_bfloat16* gA = (__hip_bfloat16*)alloc((size_t)N * 64 * 2);
    __hip_bfloat16* gB = (__hip_bfloat16*)alloc((size_t)N * 64 * 2);

    detect_kernel<<<1, 256, 0, stream>>>((const unsigned*)eidx, sflag);
    init_int_kernel<<<(N + 255) / 256, 256, 0, stream>>>(cnt, N);
    init_int_kernel<<<(M8 + 255) / 256, 256, 0, stream>>>(hist8, M8);
    passA_kernel<<<NBLOCKS, 256, 0, stream>>>(eidx, sflag, cnt, hist8, E, NB, EPB);
    dinv_kernel<<<(N + 255) / 256, 256, 0, stream>>>(cnt, dinv, N);
    int nb = (N + 1023) / 1024;
    scan1_kernel<<<nb, 256, 0, stream>>>(cnt, offs, bsums, N);
    scan2_kernel<<<1, 256, 0, stream>>>(bsums, nb);
    scan3_kernel<<<nb, 256, 0, stream>>>(offs, bsums, N, E);
    pscan_kernel<<<1, 256, 0, stream>>>(hist8, pbase, pcur, M8, E);
    passB_kernel<<<NBLOCKS, 256, 0, stream>>>(eidx, sflag, pcur, pairs, E, NB, EPB);
    passC_kernel<<<NB, 256, 0, stream>>>(pairs, pbase, offs, csr_src, N, NB);

    wconv_kernel<<<(256 * 256 + 255) / 256, 256, 0, stream>>>(W1, W1t, 256, 256);
    wconv_kernel<<<(64 * 256 + 255) / 256, 256, 0, stream>>>(W2, W2t, 256, 64);

    for (int ms = 0; ms < N; ms += CH) {
        int mc = (N - ms < CH) ? (N - ms) : CH;
        int gb = (mc + 127) / 128;
        gemm1_kernel<<<gb, 256, 0, stream>>>(x + (size_t)ms * 256, W1t, b1, h1, mc);
        gemm2_kernel<<<gb, 256, 0, stream>>>(h1, W2t, b2, hA + (size_t)ms * 64, mc);
    }

    int nwb = (N + 3) / 4;  // 4 waves (=4 dest nodes) per 256-thread block
    hop0_kernel<<<nwb, 256, 0, stream>>>(hA, dinv, pw, pb, out, gA, N);
    __hip_bfloat16* gin = gA;
    __hip_bfloat16* gout = gB;
    for (int k = 0; k < 10; ++k) {
        spmm_kernel<<<nwb, 256, 0, stream>>>(offs, csr_src, dinv, gin, gout, out, pw, pb, N);
        __hip_bfloat16* t = gin; gin = gout; gout = t;
    }
}

// Round 7
// 1214.613 us; speedup vs baseline: 1.2660x; 1.2660x over previous
//
#include <hip/hip_runtime.h>
#include <hip/hip_bf16.h>
#include <math.h>

// DAGNN r7: CSR build with ZERO per-edge global atomics.
// passA: per-block LDS bucket histogram -> blk_cnt[bucket][block]
// scan(blk_cnt) -> exact per-(bucket,block) windows (bucket windows contiguous)
// passB: LDS-cursor scatter of (r,c) pairs into private sub-windows
// passD: per-bucket LDS node counts -> cnt ; scan -> offs
// passC: per-bucket LDS-cursor scatter of src into final CSR
// MLP: bf16 MFMA GEMMs (r6). spmm: r3 form (bf16 state, wave per dest).

#define WAVE 64
#define NBLK 1024   // blocks in passA/passB; must match between them

__device__ inline float bf2f(unsigned short u) {
    union { unsigned int i; float f; } v; v.i = ((unsigned int)u) << 16; return v.f;
}
__device__ inline unsigned short f2bf(float f) {
    __hip_bfloat16 b = __float2bfloat16(f);
    union { __hip_bfloat16 b; unsigned short u; } v; v.b = b; return v.u;
}

typedef __attribute__((ext_vector_type(8))) short bf16x8;
typedef __attribute__((ext_vector_type(16))) float f32x16;

// ---- edge dtype detection: stride 1 (int32) or 2 (int64 low words) ----
__global__ void detect_kernel(const unsigned* __restrict__ e, int* __restrict__ sflag) {
    __shared__ int any;
    if (threadIdx.x == 0) any = 0;
    __syncthreads();
    unsigned nz = 0;
    int t = threadIdx.x;
    for (int i = 0; i < 8; ++i) nz |= e[(size_t)(t * 8 + i) * 2 + 1];
    if (nz) atomicOr(&any, 1);
    __syncthreads();
    if (t == 0) *sflag = any ? 1 : 2;
}

// ---- passA: per-block LDS bucket histogram (no global atomics) ----
__global__ void passA_kernel(const int* __restrict__ eidx, const int* __restrict__ sflag,
                             int* __restrict__ blk_cnt, int E, int NB, int EPB) {
    __shared__ int lh[512];
    int t = threadIdx.x, blk = blockIdx.x;
    for (int i = t; i < NB; i += 256) lh[i] = 0;
    __syncthreads();
    int s = *sflag;
    int base = blk * EPB;
    int end = base + EPB; if (end > E) end = E;
    for (int e = base + t; e < end; e += 256) {
        int c = eidx[(size_t)s * (size_t)(E + e)];
        atomicAdd(&lh[c >> 8], 1);
    }
    __syncthreads();
    for (int i = t; i < NB; i += 256)
        blk_cnt[(size_t)i * NBLK + blk] = lh[i];
}

// ---- generic scan kernels ----
// scan1: per-1024-chunk exclusive scan (in-place safe), chunk sums to bsums
__global__ void scan1_kernel(const int* __restrict__ in, int* __restrict__ out,
                             int* __restrict__ bsums, int n) {
    __shared__ int s[256];
    int t = threadIdx.x;
    int idx = blockIdx.x * 1024 + t * 4;
    int x0 = (idx + 0 < n) ? in[idx + 0] : 0;
    int x1 = (idx + 1 < n) ? in[idx + 1] : 0;
    int x2 = (idx + 2 < n) ? in[idx + 2] : 0;
    int x3 = (idx + 3 < n) ? in[idx + 3] : 0;
    int lsum = x0 + x1 + x2 + x3;
    s[t] = lsum;
    __syncthreads();
    for (int o = 1; o < 256; o <<= 1) {
        int v = (t >= o) ? s[t - o] : 0;
        __syncthreads();
        if (t >= o) s[t] += v;
        __syncthreads();
    }
    int excl = s[t] - lsum;
    if (idx + 0 < n) out[idx + 0] = excl;
    if (idx + 1 < n) out[idx + 1] = excl + x0;
    if (idx + 2 < n) out[idx + 2] = excl + x0 + x1;
    if (idx + 3 < n) out[idx + 3] = excl + x0 + x1 + x2;
    if (t == 255) bsums[blockIdx.x] = s[255];
}

// scan2g: exclusive scan of up to 1024 block sums (4 per thread)
__global__ void scan2g_kernel(int* __restrict__ bsums, int nb) {
    __shared__ int part[256];
    int t = threadIdx.x;
    int v[4]; int run = 0;
    #pragma unroll
    for (int j = 0; j < 4; ++j) {
        int i = t * 4 + j;
        int x = (i < nb) ? bsums[i] : 0;
        v[j] = run; run += x;
    }
    part[t] = run;
    __syncthreads();
    for (int o = 1; o < 256; o <<= 1) {
        int x = (t >= o) ? part[t - o] : 0;
        __syncthreads();
        if (t >= o) part[t] += x;
        __syncthreads();
    }
    int excl = part[t] - run;
    #pragma unroll
    for (int j = 0; j < 4; ++j) {
        int i = t * 4 + j;
        if (i < nb) bsums[i] = excl + v[j];
    }
}

// scan3: add block offsets; arr[n] = total
__global__ void scan3_kernel(int* __restrict__ arr, const int* __restrict__ bsums,
                             int n, int total) {
    int t = threadIdx.x;
    int idx = blockIdx.x * 1024 + t * 4;
    int add = bsums[blockIdx.x];
    #pragma unroll
    for (int i = 0; i < 4; ++i)
        if (idx + i < n) arr[idx + i] += add;
    if (blockIdx.x == 0 && t == 0) arr[n] = total;
}

// ---- passB: LDS-cursor pair scatter into private (bucket,block) windows ----
__global__ void passB_kernel(const int* __restrict__ eidx, const int* __restrict__ sflag,
                             const int* __restrict__ pbase, int2* __restrict__ pairs,
                             int E, int NB, int EPB) {
    __shared__ int lcur[512];
    int t = threadIdx.x, blk = blockIdx.x;
    for (int i = t; i < NB; i += 256) lcur[i] = pbase[(size_t)i * NBLK + blk];
    __syncthreads();
    int s = *sflag;
    int base = blk * EPB;
    int end = base + EPB; if (end > E) end = E;
    for (int e = base + t; e < end; e += 256) {
        int r = eidx[(size_t)s * (size_t)e];
        int c = eidx[(size_t)s * (size_t)(E + e)];
        int pos = atomicAdd(&lcur[c >> 8], 1);
        pairs[pos] = make_int2(r, c);
    }
}

// ---- passD: per-bucket node degree counts from bucketed pairs ----
__global__ void passD_kernel(const int2* __restrict__ pairs, const int* __restrict__ pbase,
                             int* __restrict__ cnt, int N) {
    __shared__ int lcnt[256];
    int b = blockIdx.x, t = threadIdx.x;
    lcnt[t] = 0;
    __syncthreads();
    int w0 = pbase[(size_t)b * NBLK], w1 = pbase[(size_t)(b + 1) * NBLK];
    for (int i = w0 + t; i < w1; i += 256)
        atomicAdd(&lcnt[pairs[i].y & 255], 1);
    __syncthreads();
    int node = b * 256 + t;
    if (node < N) cnt[node] = lcnt[t];
}

__global__ void dinv_kernel(const int* __restrict__ cnt, float* __restrict__ dinv, int n) {
    int i = blockIdx.x * blockDim.x + threadIdx.x;
    if (i < n) dinv[i] = rsqrtf((float)(cnt[i] + 1));  // self-loop adds 1
}

// ---- passC: per-bucket LDS cursors, scatter src into final CSR window ----
__global__ void passC_kernel(const int2* __restrict__ pairs, const int* __restrict__ pbase,
                             const int* __restrict__ offs, int* __restrict__ csr_src,
                             int N) {
    __shared__ int lcur[256];
    int b = blockIdx.x, t = threadIdx.x;
    int node = b * 256 + t;
    lcur[t] = (node < N) ? offs[node] : 0;
    __syncthreads();
    int w0 = pbase[(size_t)b * NBLK], w1 = pbase[(size_t)(b + 1) * NBLK];
    for (int i = w0 + t; i < w1; i += 256) {
        int2 p = pairs[i];
        int pos = atomicAdd(&lcur[p.y & 255], 1);
        csr_src[pos] = p.x;
    }
}

// ---- weight convert+transpose: Wt[n][k] = bf16(W[k][n]) ----
__global__ void wconv_kernel(const float* __restrict__ W, unsigned short* __restrict__ Wt,
                             int K, int Nn) {
    int i = blockIdx.x * blockDim.x + threadIdx.x;
    if (i >= K * Nn) return;
    int n = i / K, k = i - n * K;
    Wt[(size_t)n * K + k] = f2bf(W[(size_t)k * Nn + n]);
}

// ---- GEMM1: A fp32 [M][256] x W1t bf16 [256][256] -> h1 bf16 [M][256], relu ----
__global__ __launch_bounds__(256) void gemm1_kernel(
        const float* __restrict__ A, const unsigned short* __restrict__ Bt,
        const float* __restrict__ bias, unsigned short* __restrict__ C, int M) {
    __shared__ unsigned short Asub[128][40];
    __shared__ unsigned short Bsub[256][40];
    int tid = threadIdx.x;
    int wave = tid >> 6, lane = tid & 63;
    int wm = wave >> 1, wn = wave & 1;
    int bm = blockIdx.x * 128;
    int half = lane >> 5, l31 = lane & 31;

    f32x16 acc[2][4] = {};

    for (int k0 = 0; k0 < 256; k0 += 32) {
        #pragma unroll
        for (int i = 0; i < 4; ++i) {
            int f = i * 256 + tid;
            int row = f >> 3, c4 = (f & 7) * 4;
            int grow = bm + row;
            float4 v = make_float4(0.f, 0.f, 0.f, 0.f);
            if (grow < M) v = *(const float4*)(A + (size_t)grow * 256 + k0 + c4);
            ushort4 uu;
            uu.x = f2bf(v.x); uu.y = f2bf(v.y); uu.z = f2bf(v.z); uu.w = f2bf(v.w);
            *(ushort4*)&Asub[row][c4] = uu;
        }
        {
            const unsigned short* p = Bt + (size_t)tid * 256 + k0;
            uint4 u0 = *(const uint4*)(p);
            uint4 u1 = *(const uint4*)(p + 8);
            uint4 u2 = *(const uint4*)(p + 16);
            uint4 u3 = *(const uint4*)(p + 24);
            *(uint4*)&Bsub[tid][0]  = u0;
            *(uint4*)&Bsub[tid][8]  = u1;
            *(uint4*)&Bsub[tid][16] = u2;
            *(uint4*)&Bsub[tid][24] = u3;
        }
        __syncthreads();
        #pragma unroll
        for (int ks = 0; ks < 32; ks += 16) {
            bf16x8 a0 = *(bf16x8*)&Asub[wm * 64 + l31][ks + half * 8];
            bf16x8 a1 = *(bf16x8*)&Asub[wm * 64 + 32 + l31][ks + half * 8];
            #pragma unroll
            for (int j = 0; j < 4; ++j) {
                bf16x8 bf = *(bf16x8*)&Bsub[wn * 128 + j * 32 + l31][ks + half * 8];
                acc[0][j] = __builtin_amdgcn_mfma_f32_32x32x16_bf16(a0, bf, acc[0][j], 0, 0, 0);
                acc[1][j] = __builtin_amdgcn_mfma_f32_32x32x16_bf16(a1, bf, acc[1][j], 0, 0, 0);
            }
        }
        __syncthreads();
    }

    #pragma unroll
    for (int j = 0; j < 4; ++j) {
        int col = wn * 128 + j * 32 + l31;
        float bv = bias[col];
        #pragma unroll
        for (int mt = 0; mt < 2; ++mt) {
            #pragma unroll
            for (int reg = 0; reg < 16; ++reg) {
                int rowin = (reg & 3) + 8 * (reg >> 2) + 4 * half;
                int grow = bm + wm * 64 + mt * 32 + rowin;
                if (grow < M) {
                    float v = fmaxf(acc[mt][j][reg] + bv, 0.f);
                    C[(size_t)grow * 256 + col] = f2bf(v);
                }
            }
        }
    }
}

// ---- GEMM2: h1 bf16 [M][256] x W2t bf16 [64][256] -> hA fp32 [M][64] ----
__global__ __launch_bounds__(256) void gemm2_kernel(
        const unsigned short* __restrict__ A, const unsigned short* __restrict__ Bt,
        const float* __restrict__ bias, float* __restrict__ C, int M) {
    __shared__ unsigned short Asub[128][40];
    __shared__ unsigned short Bsub[64][40];
    int tid = threadIdx.x;
    int wave = tid >> 6, lane = tid & 63;
    int bm = blockIdx.x * 128;
    int half = lane >> 5, l31 = lane & 31;

    f32x16 acc[2] = {};

    for (int k0 = 0; k0 < 256; k0 += 32) {
        #pragma unroll
        for (int i = 0; i < 2; ++i) {
            int f = i * 256 + tid;
            int row = f >> 2, c8 = (f & 3) * 8;
            int grow = bm + row;
            uint4 u = make_uint4(0, 0, 0, 0);
            if (grow < M) u = *(const uint4*)(A + (size_t)grow * 256 + k0 + c8);
            *(uint4*)&Asub[row][c8] = u;
        }
        {
            int n = tid >> 2, k8 = (tid & 3) * 8;
            uint4 u = *(const uint4*)(Bt + (size_t)n * 256 + k0 + k8);
            *(uint4*)&Bsub[n][k8] = u;
        }
        __syncthreads();
        #pragma unroll
        for (int ks = 0; ks < 32; ks += 16) {
            bf16x8 a = *(bf16x8*)&Asub[wave * 32 + l31][ks + half * 8];
            #pragma unroll
            for (int j = 0; j < 2; ++j) {
                bf16x8 bf = *(bf16x8*)&Bsub[j * 32 + l31][ks + half * 8];
                acc[j] = __builtin_amdgcn_mfma_f32_32x32x16_bf16(a, bf, acc[j], 0, 0, 0);
            }
        }
        __syncthreads();
    }

    #pragma unroll
    for (int j = 0; j < 2; ++j) {
        int col = j * 32 + l31;
        float bv = bias[col];
        #pragma unroll
        for (int reg = 0; reg < 16; ++reg) {
            int rowin = (reg & 3) + 8 * (reg >> 2) + 4 * half;
            int grow = bm + wave * 32 + rowin;
            if (grow < M) C[(size_t)grow * 64 + col] = acc[j][reg] + bv;
        }
    }
}

// ---- hop 0: out = sigmoid(h.pw + pb)*h ; g0 = bf16(dinv*h) ----
__global__ void hop0_kernel(const float* __restrict__ h, const float* __restrict__ dinv,
                            const float* __restrict__ pw, const float* __restrict__ pb,
                            float* __restrict__ out, __hip_bfloat16* __restrict__ g, int n) {
    int wid = (blockIdx.x * blockDim.x + threadIdx.x) >> 6;
    int lane = threadIdx.x & 63;
    if (wid >= n) return;
    float v = h[(size_t)wid * 64 + lane];
    float d = v * pw[lane];
    #pragma unroll
    for (int o = 32; o > 0; o >>= 1) d += __shfl_xor(d, o, 64);
    float sg = 1.f / (1.f + __expf(-(d + pb[0])));
    out[(size_t)wid * 64 + lane] = sg * v;
    g[(size_t)wid * 64 + lane] = __float2bfloat16(dinv[wid] * v);
}

// ---- one hop (r3 form): wave per dest, uniform edge indices, bf16 gathers ----
__global__ void spmm_kernel(const int* __restrict__ offs, const int* __restrict__ src,
                            const float* __restrict__ dinv,
                            const __hip_bfloat16* __restrict__ gin,
                            __hip_bfloat16* __restrict__ gout,
                            float* __restrict__ out,
                            const float* __restrict__ pw, const float* __restrict__ pb,
                            int n) {
    int wid = (blockIdx.x * blockDim.x + threadIdx.x) >> 6;
    int lane = threadIdx.x & 63;
    if (wid >= n) return;
    int c = __builtin_amdgcn_readfirstlane(wid);
    int e = __builtin_amdgcn_readfirstlane(offs[c]);
    int eend = __builtin_amdgcn_readfirstlane(offs[c + 1]);
    float acc = 0.f;
    while (e < eend && (e & 3)) {
        acc += __bfloat162float(gin[(size_t)src[e] * 64 + lane]);
        ++e;
    }
    for (; e + 7 < eend; e += 8) {
        int4 sa = *(const int4*)(src + e);
        int4 sb = *(const int4*)(src + e + 4);
        float v0 = __bfloat162float(gin[(size_t)sa.x * 64 + lane]);
        float v1 = __bfloat162float(gin[(size_t)sa.y * 64 + lane]);
        float v2 = __bfloat162float(gin[(size_t)sa.z * 64 + lane]);
        float v3 = __bfloat162float(gin[(size_t)sa.w * 64 + lane]);
        float v4 = __bfloat162float(gin[(size_t)sb.x * 64 + lane]);
        float v5 = __bfloat162float(gin[(size_t)sb.y * 64 + lane]);
        float v6 = __bfloat162float(gin[(size_t)sb.z * 64 + lane]);
        float v7 = __bfloat162float(gin[(size_t)sb.w * 64 + lane]);
        acc += ((v0 + v1) + (v2 + v3)) + ((v4 + v5) + (v6 + v7));
    }
    for (; e + 3 < eend; e += 4) {
        int4 sa = *(const int4*)(src + e);
        float v0 = __bfloat162float(gin[(size_t)sa.x * 64 + lane]);
        float v1 = __bfloat162float(gin[(size_t)sa.y * 64 + lane]);
        float v2 = __bfloat162float(gin[(size_t)sa.z * 64 + lane]);
        float v3 = __bfloat162float(gin[(size_t)sa.w * 64 + lane]);
        acc += (v0 + v1) + (v2 + v3);
    }
    for (; e < eend; ++e) acc += __bfloat162float(gin[(size_t)src[e] * 64 + lane]);

    float dc = dinv[c];
    float h = dc * (acc + __bfloat162float(gin[(size_t)c * 64 + lane]));
    gout[(size_t)c * 64 + lane] = __float2bfloat16(dc * h);
    float d = h * pw[lane];
    #pragma unroll
    for (int o = 32; o > 0; o >>= 1) d += __shfl_xor(d, o, 64);
    float sg = 1.f / (1.f + __expf(-(d + pb[0])));
    out[(size_t)c * 64 + lane] += sg * h;
}

extern "C" void kernel_launch(void* const* d_in, const int* in_sizes, int n_in,
                              void* d_out, int out_size, void* d_ws, size_t ws_size,
                              hipStream_t stream) {
    const float* x  = (const float*)d_in[0];
    const int* eidx = (const int*)d_in[1];
    const float* W1 = (const float*)d_in[2];
    const float* b1 = (const float*)d_in[3];
    const float* W2 = (const float*)d_in[4];
    const float* b2 = (const float*)d_in[5];
    const float* pw = (const float*)d_in[6];
    const float* pb = (const float*)d_in[7];
    float* out = (float*)d_out;

    const int N = in_sizes[0] / 256;
    const int E = in_sizes[1] / 2;
    const int NB = (N + 255) >> 8;              // buckets of 256 dest nodes
    const int EPB = (E + NBLK - 1) / NBLK;      // edges per passA/passB block
    const int M = NB * NBLK;                    // blk_cnt entries

    size_t woff = 0;
    auto alloc = [&](size_t bytes) -> void* {
        void* p = (char*)d_ws + woff;
        woff += (bytes + 255) & ~(size_t)255;
        return p;
    };
    int*   sflag   = (int*)alloc(4);
    int*   cnt     = (int*)alloc((size_t)N * 4);
    float* dinv    = (float*)alloc((size_t)N * 4);
    int*   offs    = (int*)alloc(((size_t)N + 1) * 4);
    int*   bsums   = (int*)alloc(1024 * 4);
    int*   bsums2  = (int*)alloc(1024 * 4);
    int*   pbase   = (int*)alloc(((size_t)M + 1) * 4);
    int*   csr_src = (int*)alloc((size_t)E * 4);
    int2*  pairs   = (int2*)alloc((size_t)E * 8);
    unsigned short* W1t = (unsigned short*)alloc((size_t)256 * 256 * 2);
    unsigned short* W2t = (unsigned short*)alloc((size_t)64 * 256 * 2);
    const int CH = 50000;
    unsigned short* h1 = (unsigned short*)alloc((size_t)CH * 256 * 2);
    float* hA = (float*)alloc((size_t)N * 64 * 4);
    __hip_bfloat16* gA = (__hip_bfloat16*)alloc((size_t)N * 64 * 2);
    __hip_bfloat16* gB = (__hip_bfloat16*)alloc((size_t)N * 64 * 2);

    detect_kernel<<<1, 256, 0, stream>>>((const unsigned*)eidx, sflag);

    // build: histogram -> scan -> pair scatter -> node counts -> offs -> CSR
    passA_kernel<<<NBLK, 256, 0, stream>>>(eidx, sflag, pbase, E, NB, EPB);
    int nb2 = (M + 1023) / 1024;
    scan1_kernel<<<nb2, 256, 0, stream>>>(pbase, pbase, bsums2, M);
    scan2g_kernel<<<1, 256, 0, stream>>>(bsums2, nb2);
    scan3_kernel<<<nb2, 256, 0, stream>>>(pbase, bsums2, M, E);
    passB_kernel<<<NBLK, 256, 0, stream>>>(eidx, sflag, pbase, pairs, E, NB, EPB);
    passD_kernel<<<NB, 256, 0, stream>>>(pairs, pbase, cnt, N);
    dinv_kernel<<<(N + 255) / 256, 256, 0, stream>>>(cnt, dinv, N);
    int nb1 = (N + 1023) / 1024;
    scan1_kernel<<<nb1, 256, 0, stream>>>(cnt, offs, bsums, N);
    scan2g_kernel<<<1, 256, 0, stream>>>(bsums, nb1);
    scan3_kernel<<<nb1, 256, 0, stream>>>(offs, bsums, N, E);
    passC_kernel<<<NB, 256, 0, stream>>>(pairs, pbase, offs, csr_src, N);

    // MLP
    wconv_kernel<<<(256 * 256 + 255) / 256, 256, 0, stream>>>(W1, W1t, 256, 256);
    wconv_kernel<<<(64 * 256 + 255) / 256, 256, 0, stream>>>(W2, W2t, 256, 64);
    for (int ms = 0; ms < N; ms += CH) {
        int mc = (N - ms < CH) ? (N - ms) : CH;
        int gb = (mc + 127) / 128;
        gemm1_kernel<<<gb, 256, 0, stream>>>(x + (size_t)ms * 256, W1t, b1, h1, mc);
        gemm2_kernel<<<gb, 256, 0, stream>>>(h1, W2t, b2, hA + (size_t)ms * 64, mc);
    }

    // propagation + fused pooling
    int nwb = (N + 3) / 4;  // 4 waves (=4 dest nodes) per 256-thread block
    hop0_kernel<<<nwb, 256, 0, stream>>>(hA, dinv, pw, pb, out, gA, N);
    __hip_bfloat16* gin = gA;
    __hip_bfloat16* gout = gB;
    for (int k = 0; k < 10; ++k) {
        spmm_kernel<<<nwb, 256, 0, stream>>>(offs, csr_src, dinv, gin, gout, out, pw, pb, N);
        __hip_bfloat16* t = gin; gin = gout; gout = t;
    }
}

// Round 8
// 1149.539 us; speedup vs baseline: 1.3376x; 1.0566x over previous
//
#include <hip/hip_runtime.h>
#include <hip/hip_bf16.h>
#include <math.h>

// DAGNN r8: fused MLP kernel (gemm1+gemm2+hop0 in one dispatch):
//  - h1 tile lives in LDS (fragment-major, conflict-minimal), no global round-trip
//  - x loads register-prefetched across the k-loop
//  - pooling epilogue writes out and g0 directly (hop0/hA deleted)
// Build: r7 zero-global-atomic bucket sort. spmm: r3 form (bf16 state).

#define WAVE 64
#define NBLK 1024   // blocks in passA/passB; must match between them

__device__ inline float bf2f(unsigned short u) {
    union { unsigned int i; float f; } v; v.i = ((unsigned int)u) << 16; return v.f;
}
__device__ inline unsigned short f2bf(float f) {
    __hip_bfloat16 b = __float2bfloat16(f);
    union { __hip_bfloat16 b; unsigned short u; } v; v.b = b; return v.u;
}

typedef __attribute__((ext_vector_type(8))) short bf16x8;
typedef __attribute__((ext_vector_type(16))) float f32x16;

// ---- edge dtype detection: stride 1 (int32) or 2 (int64 low words) ----
__global__ void detect_kernel(const unsigned* __restrict__ e, int* __restrict__ sflag) {
    __shared__ int any;
    if (threadIdx.x == 0) any = 0;
    __syncthreads();
    unsigned nz = 0;
    int t = threadIdx.x;
    for (int i = 0; i < 8; ++i) nz |= e[(size_t)(t * 8 + i) * 2 + 1];
    if (nz) atomicOr(&any, 1);
    __syncthreads();
    if (t == 0) *sflag = any ? 1 : 2;
}

// ---- passA: per-block LDS bucket histogram (no global atomics) ----
__global__ void passA_kernel(const int* __restrict__ eidx, const int* __restrict__ sflag,
                             int* __restrict__ blk_cnt, int E, int NB, int EPB) {
    __shared__ int lh[512];
    int t = threadIdx.x, blk = blockIdx.x;
    for (int i = t; i < NB; i += 256) lh[i] = 0;
    __syncthreads();
    int s = *sflag;
    int base = blk * EPB;
    int end = base + EPB; if (end > E) end = E;
    for (int e = base + t; e < end; e += 256) {
        int c = eidx[(size_t)s * (size_t)(E + e)];
        atomicAdd(&lh[c >> 8], 1);
    }
    __syncthreads();
    for (int i = t; i < NB; i += 256)
        blk_cnt[(size_t)i * NBLK + blk] = lh[i];
}

// ---- scans ----
__global__ void scan1_kernel(const int* __restrict__ in, int* __restrict__ out,
                             int* __restrict__ bsums, int n) {
    __shared__ int s[256];
    int t = threadIdx.x;
    int idx = blockIdx.x * 1024 + t * 4;
    int x0 = (idx + 0 < n) ? in[idx + 0] : 0;
    int x1 = (idx + 1 < n) ? in[idx + 1] : 0;
    int x2 = (idx + 2 < n) ? in[idx + 2] : 0;
    int x3 = (idx + 3 < n) ? in[idx + 3] : 0;
    int lsum = x0 + x1 + x2 + x3;
    s[t] = lsum;
    __syncthreads();
    for (int o = 1; o < 256; o <<= 1) {
        int v = (t >= o) ? s[t - o] : 0;
        __syncthreads();
        if (t >= o) s[t] += v;
        __syncthreads();
    }
    int excl = s[t] - lsum;
    if (idx + 0 < n) out[idx + 0] = excl;
    if (idx + 1 < n) out[idx + 1] = excl + x0;
    if (idx + 2 < n) out[idx + 2] = excl + x0 + x1;
    if (idx + 3 < n) out[idx + 3] = excl + x0 + x1 + x2;
    if (t == 255) bsums[blockIdx.x] = s[255];
}

__global__ void scan2g_kernel(int* __restrict__ bsums, int nb) {
    __shared__ int part[256];
    int t = threadIdx.x;
    int v[4]; int run = 0;
    #pragma unroll
    for (int j = 0; j < 4; ++j) {
        int i = t * 4 + j;
        int x = (i < nb) ? bsums[i] : 0;
        v[j] = run; run += x;
    }
    part[t] = run;
    __syncthreads();
    for (int o = 1; o < 256; o <<= 1) {
        int x = (t >= o) ? part[t - o] : 0;
        __syncthreads();
        if (t >= o) part[t] += x;
        __syncthreads();
    }
    int excl = part[t] - run;
    #pragma unroll
    for (int j = 0; j < 4; ++j) {
        int i = t * 4 + j;
        if (i < nb) bsums[i] = excl + v[j];
    }
}

__global__ void scan3_kernel(int* __restrict__ arr, const int* __restrict__ bsums,
                             int n, int total) {
    int t = threadIdx.x;
    int idx = blockIdx.x * 1024 + t * 4;
    int add = bsums[blockIdx.x];
    #pragma unroll
    for (int i = 0; i < 4; ++i)
        if (idx + i < n) arr[idx + i] += add;
    if (blockIdx.x == 0 && t == 0) arr[n] = total;
}

// ---- passB: LDS-cursor pair scatter into private (bucket,block) windows ----
__global__ void passB_kernel(const int* __restrict__ eidx, const int* __restrict__ sflag,
                             const int* __restrict__ pbase, int2* __restrict__ pairs,
                             int E, int NB, int EPB) {
    __shared__ int lcur[512];
    int t = threadIdx.x, blk = blockIdx.x;
    for (int i = t; i < NB; i += 256) lcur[i] = pbase[(size_t)i * NBLK + blk];
    __syncthreads();
    int s = *sflag;
    int base = blk * EPB;
    int end = base + EPB; if (end > E) end = E;
    for (int e = base + t; e < end; e += 256) {
        int r = eidx[(size_t)s * (size_t)e];
        int c = eidx[(size_t)s * (size_t)(E + e)];
        int pos = atomicAdd(&lcur[c >> 8], 1);
        pairs[pos] = make_int2(r, c);
    }
}

// ---- passD: per-bucket node degree counts from bucketed pairs ----
__global__ void passD_kernel(const int2* __restrict__ pairs, const int* __restrict__ pbase,
                             int* __restrict__ cnt, int N) {
    __shared__ int lcnt[256];
    int b = blockIdx.x, t = threadIdx.x;
    lcnt[t] = 0;
    __syncthreads();
    int w0 = pbase[(size_t)b * NBLK], w1 = pbase[(size_t)(b + 1) * NBLK];
    for (int i = w0 + t; i < w1; i += 256)
        atomicAdd(&lcnt[pairs[i].y & 255], 1);
    __syncthreads();
    int node = b * 256 + t;
    if (node < N) cnt[node] = lcnt[t];
}

__global__ void dinv_kernel(const int* __restrict__ cnt, float* __restrict__ dinv, int n) {
    int i = blockIdx.x * blockDim.x + threadIdx.x;
    if (i < n) dinv[i] = rsqrtf((float)(cnt[i] + 1));  // self-loop adds 1
}

// ---- passC: per-bucket LDS cursors, scatter src into final CSR window ----
__global__ void passC_kernel(const int2* __restrict__ pairs, const int* __restrict__ pbase,
                             const int* __restrict__ offs, int* __restrict__ csr_src,
                             int N) {
    __shared__ int lcur[256];
    int b = blockIdx.x, t = threadIdx.x;
    int node = b * 256 + t;
    lcur[t] = (node < N) ? offs[node] : 0;
    __syncthreads();
    int w0 = pbase[(size_t)b * NBLK], w1 = pbase[(size_t)(b + 1) * NBLK];
    for (int i = w0 + t; i < w1; i += 256) {
        int2 p = pairs[i];
        int pos = atomicAdd(&lcur[p.y & 255], 1);
        csr_src[pos] = p.x;
    }
}

// ---- weight convert+transpose: Wt[n][k] = bf16(W[k][n]) ----
__global__ void wconv_kernel(const float* __restrict__ W, unsigned short* __restrict__ Wt,
                             int K, int Nn) {
    int i = blockIdx.x * blockDim.x + threadIdx.x;
    if (i >= K * Nn) return;
    int n = i / K, k = i - n * K;
    Wt[(size_t)n * K + k] = f2bf(W[(size_t)k * Nn + n]);
}

// ---- fused MLP: h = relu(x@W1+b1)@W2+b2 ; out = sigmoid(h.pw+pb)*h ;
//      g0 = bf16(dinv*h).  BM=128 rows/block, 256 thr (4 waves).
// LDS fragment-major layouts: [k16][half][row][8 bf16] (16B lane-contiguous). ----
__global__ __launch_bounds__(256, 1) void mlp_fused(
        const float* __restrict__ x,
        const unsigned short* __restrict__ W1t,   // [256 n][256 k] bf16
        const float* __restrict__ b1,
        const unsigned short* __restrict__ W2t,   // [64 n][256 k] bf16
        const float* __restrict__ b2,
        const float* __restrict__ dinv,
        const float* __restrict__ pw, const float* __restrict__ pb,
        float* __restrict__ out, unsigned short* __restrict__ g,
        int M) {
    __shared__ unsigned short xfrag[2][2][128 * 8];
    __shared__ unsigned short w1frag[2][2][256 * 8];
    __shared__ unsigned short h1frag[16][2][128 * 8];
    __shared__ unsigned short w2frag[16][2][64 * 8];

    int tid = threadIdx.x;
    int wave = tid >> 6, lane = tid & 63;
    int half = lane >> 5, l31 = lane & 31;
    int wm = wave >> 1, wn = wave & 1;
    int bm = blockIdx.x * 128;

    // stage W2 once (visible after first __syncthreads)
    #pragma unroll
    for (int i = 0; i < 8; ++i) {
        int F = i * 256 + tid;               // 0..2047 fragments
        int s = F >> 7, hf = (F >> 6) & 1, n = F & 63;
        uint4 u = *(const uint4*)(W2t + (size_t)n * 256 + s * 16 + hf * 8);
        *(uint4*)&w2frag[s][hf][n * 8] = u;
    }

    f32x16 acc1[2][4] = {};

    float4 xv[4];
    uint4 wv[4];
    // prefetch k0 = 0
    #pragma unroll
    for (int i = 0; i < 4; ++i) {
        int f = i * 256 + tid;
        int row = f >> 3, c4 = (f & 7) * 4;
        int grow = bm + row;
        xv[i] = (grow < M) ? *(const float4*)(x + (size_t)grow * 256 + c4)
                           : make_float4(0.f, 0.f, 0.f, 0.f);
    }
    {
        const unsigned short* p = W1t + (size_t)tid * 256;
        wv[0] = *(const uint4*)(p);
        wv[1] = *(const uint4*)(p + 8);
        wv[2] = *(const uint4*)(p + 16);
        wv[3] = *(const uint4*)(p + 24);
    }

    for (int it = 0; it < 8; ++it) {
        // commit prefetched tile to LDS
        #pragma unroll
        for (int i = 0; i < 4; ++i) {
            int f = i * 256 + tid;
            int row = f >> 3, c4 = (f & 7) * 4;
            int k16 = c4 >> 4, hf = (c4 >> 3) & 1, off = c4 & 7;   // off = 0 or 4 ushorts
            ushort4 u;
            u.x = f2bf(xv[i].x); u.y = f2bf(xv[i].y);
            u.z = f2bf(xv[i].z); u.w = f2bf(xv[i].w);
            *(ushort4*)&xfrag[k16][hf][row * 8 + off] = u;
        }
        #pragma unroll
        for (int q = 0; q < 4; ++q)
            *(uint4*)&w1frag[q >> 1][q & 1][tid * 8] = wv[q];
        __syncthreads();
        // prefetch next tile while MFMAs run
        if (it < 7) {
            int k0 = (it + 1) * 32;
            #pragma unroll
            for (int i = 0; i < 4; ++i) {
                int f = i * 256 + tid;
                int row = f >> 3, c4 = (f & 7) * 4;
                int grow = bm + row;
                xv[i] = (grow < M) ? *(const float4*)(x + (size_t)grow * 256 + k0 + c4)
                                   : make_float4(0.f, 0.f, 0.f, 0.f);
            }
            const unsigned short* p = W1t + (size_t)tid * 256 + k0;
            wv[0] = *(const uint4*)(p);
            wv[1] = *(const uint4*)(p + 8);
            wv[2] = *(const uint4*)(p + 16);
            wv[3] = *(const uint4*)(p + 24);
        }
        #pragma unroll
        for (int s = 0; s < 2; ++s) {
            bf16x8 a0 = *(bf16x8*)&xfrag[s][half][(wm * 64 + l31) * 8];
            bf16x8 a1 = *(bf16x8*)&xfrag[s][half][(wm * 64 + 32 + l31) * 8];
            #pragma unroll
            for (int j = 0; j < 4; ++j) {
                bf16x8 b = *(bf16x8*)&w1frag[s][half][(wn * 128 + j * 32 + l31) * 8];
                acc1[0][j] = __builtin_amdgcn_mfma_f32_32x32x16_bf16(a0, b, acc1[0][j], 0, 0, 0);
                acc1[1][j] = __builtin_amdgcn_mfma_f32_32x32x16_bf16(a1, b, acc1[1][j], 0, 0, 0);
            }
        }
        __syncthreads();
    }

    // bias + relu, write h1 tile to LDS in stage-2 A-fragment layout
    #pragma unroll
    for (int j = 0; j < 4; ++j) {
        int ch = wn * 128 + j * 32 + l31;
        float bb = b1[ch];
        int k16 = ch >> 4, hf = (ch >> 3) & 1, off = ch & 7;
        #pragma unroll
        for (int mt = 0; mt < 2; ++mt) {
            #pragma unroll
            for (int reg = 0; reg < 16; ++reg) {
                int rowin = (reg & 3) + 8 * (reg >> 2) + 4 * half;
                int row = wm * 64 + mt * 32 + rowin;
                float v = fmaxf(acc1[mt][j][reg] + bb, 0.f);
                h1frag[k16][hf][row * 8 + off] = f2bf(v);
            }
        }
    }
    __syncthreads();

    // stage 2: wave owns rows wave*32 .. +31
    f32x16 acc2[2] = {};
    #pragma unroll
    for (int s = 0; s < 16; ++s) {
        bf16x8 a = *(bf16x8*)&h1frag[s][half][(wave * 32 + l31) * 8];
        #pragma unroll
        for (int j = 0; j < 2; ++j) {
            bf16x8 b = *(bf16x8*)&w2frag[s][half][(j * 32 + l31) * 8];
            acc2[j] = __builtin_amdgcn_mfma_f32_32x32x16_bf16(a, b, acc2[j], 0, 0, 0);
        }
    }

    // epilogue: bias, pooling (butterfly over l31), out + g0
    float bb0 = b2[l31], bb1 = b2[32 + l31];
    float pw0 = pw[l31], pw1 = pw[32 + l31];
    float pbv = pb[0];
    #pragma unroll
    for (int reg = 0; reg < 16; ++reg) {
        int rowin = (reg & 3) + 8 * (reg >> 2) + 4 * half;
        int row = bm + wave * 32 + rowin;
        float h0 = acc2[0][reg] + bb0;
        float h1v = acc2[1][reg] + bb1;
        float d = h0 * pw0 + h1v * pw1;
        d += __shfl_xor(d, 1, 64);
        d += __shfl_xor(d, 2, 64);
        d += __shfl_xor(d, 4, 64);
        d += __shfl_xor(d, 8, 64);
        d += __shfl_xor(d, 16, 64);
        float sg = 1.f / (1.f + __expf(-(d + pbv)));
        if (row < M) {
            float dv = dinv[row];
            out[(size_t)row * 64 + l31]      = sg * h0;
            out[(size_t)row * 64 + 32 + l31] = sg * h1v;
            g[(size_t)row * 64 + l31]        = f2bf(dv * h0);
            g[(size_t)row * 64 + 32 + l31]   = f2bf(dv * h1v);
        }
    }
}

// ---- one hop (r3 form): wave per dest, uniform edge indices, bf16 gathers ----
__global__ void spmm_kernel(const int* __restrict__ offs, const int* __restrict__ src,
                            const float* __restrict__ dinv,
                            const __hip_bfloat16* __restrict__ gin,
                            __hip_bfloat16* __restrict__ gout,
                            float* __restrict__ out,
                            const float* __restrict__ pw, const float* __restrict__ pb,
                            int n) {
    int wid = (blockIdx.x * blockDim.x + threadIdx.x) >> 6;
    int lane = threadIdx.x & 63;
    if (wid >= n) return;
    int c = __builtin_amdgcn_readfirstlane(wid);
    int e = __builtin_amdgcn_readfirstlane(offs[c]);
    int eend = __builtin_amdgcn_readfirstlane(offs[c + 1]);
    float acc = 0.f;
    while (e < eend && (e & 3)) {
        acc += __bfloat162float(gin[(size_t)src[e] * 64 + lane]);
        ++e;
    }
    for (; e + 7 < eend; e += 8) {
        int4 sa = *(const int4*)(src + e);
        int4 sb = *(const int4*)(src + e + 4);
        float v0 = __bfloat162float(gin[(size_t)sa.x * 64 + lane]);
        float v1 = __bfloat162float(gin[(size_t)sa.y * 64 + lane]);
        float v2 = __bfloat162float(gin[(size_t)sa.z * 64 + lane]);
        float v3 = __bfloat162float(gin[(size_t)sa.w * 64 + lane]);
        float v4 = __bfloat162float(gin[(size_t)sb.x * 64 + lane]);
        float v5 = __bfloat162float(gin[(size_t)sb.y * 64 + lane]);
        float v6 = __bfloat162float(gin[(size_t)sb.z * 64 + lane]);
        float v7 = __bfloat162float(gin[(size_t)sb.w * 64 + lane]);
        acc += ((v0 + v1) + (v2 + v3)) + ((v4 + v5) + (v6 + v7));
    }
    for (; e + 3 < eend; e += 4) {
        int4 sa = *(const int4*)(src + e);
        float v0 = __bfloat162float(gin[(size_t)sa.x * 64 + lane]);
        float v1 = __bfloat162float(gin[(size_t)sa.y * 64 + lane]);
        float v2 = __bfloat162float(gin[(size_t)sa.z * 64 + lane]);
        float v3 = __bfloat162float(gin[(size_t)sa.w * 64 + lane]);
        acc += (v0 + v1) + (v2 + v3);
    }
    for (; e < eend; ++e) acc += __bfloat162float(gin[(size_t)src[e] * 64 + lane]);

    float dc = dinv[c];
    float h = dc * (acc + __bfloat162float(gin[(size_t)c * 64 + lane]));
    gout[(size_t)c * 64 + lane] = __float2bfloat16(dc * h);
    float d = h * pw[lane];
    #pragma unroll
    for (int o = 32; o > 0; o >>= 1) d += __shfl_xor(d, o, 64);
    float sg = 1.f / (1.f + __expf(-(d + pb[0])));
    out[(size_t)c * 64 + lane] += sg * h;
}

extern "C" void kernel_launch(void* const* d_in, const int* in_sizes, int n_in,
                              void* d_out, int out_size, void* d_ws, size_t ws_size,
                              hipStream_t stream) {
    const float* x  = (const float*)d_in[0];
    const int* eidx = (const int*)d_in[1];
    const float* W1 = (const float*)d_in[2];
    const float* b1 = (const float*)d_in[3];
    const float* W2 = (const float*)d_in[4];
    const float* b2 = (const float*)d_in[5];
    const float* pw = (const float*)d_in[6];
    const float* pb = (const float*)d_in[7];
    float* out = (float*)d_out;

    const int N = in_sizes[0] / 256;
    const int E = in_sizes[1] / 2;
    const int NB = (N + 255) >> 8;              // buckets of 256 dest nodes
    const int EPB = (E + NBLK - 1) / NBLK;      // edges per passA/passB block
    const int M = NB * NBLK;                    // blk_cnt entries

    size_t woff = 0;
    auto alloc = [&](size_t bytes) -> void* {
        void* p = (char*)d_ws + woff;
        woff += (bytes + 255) & ~(size_t)255;
        return p;
    };
    int*   sflag   = (int*)alloc(4);
    int*   cnt     = (int*)alloc((size_t)N * 4);
    float* dinv    = (float*)alloc((size_t)N * 4);
    int*   offs    = (int*)alloc(((size_t)N + 1) * 4);
    int*   bsums   = (int*)alloc(1024 * 4);
    int*   bsums2  = (int*)alloc(1024 * 4);
    int*   pbase   = (int*)alloc(((size_t)M + 1) * 4);
    int*   csr_src = (int*)alloc((size_t)E * 4);
    int2*  pairs   = (int2*)alloc((size_t)E * 8);
    unsigned short* W1t = (unsigned short*)alloc((size_t)256 * 256 * 2);
    unsigned short* W2t = (unsigned short*)alloc((size_t)64 * 256 * 2);
    __hip_bfloat16* gA = (__hip_bfloat16*)alloc((size_t)N * 64 * 2);
    __hip_bfloat16* gB = (__hip_bfloat16*)alloc((size_t)N * 64 * 2);

    detect_kernel<<<1, 256, 0, stream>>>((const unsigned*)eidx, sflag);

    // build: histogram -> scan -> pair scatter -> node counts -> offs -> CSR
    passA_kernel<<<NBLK, 256, 0, stream>>>(eidx, sflag, pbase, E, NB, EPB);
    int nb2 = (M + 1023) / 1024;
    scan1_kernel<<<nb2, 256, 0, stream>>>(pbase, pbase, bsums2, M);
    scan2g_kernel<<<1, 256, 0, stream>>>(bsums2, nb2);
    scan3_kernel<<<nb2, 256, 0, stream>>>(pbase, bsums2, M, E);
    passB_kernel<<<NBLK, 256, 0, stream>>>(eidx, sflag, pbase, pairs, E, NB, EPB);
    passD_kernel<<<NB, 256, 0, stream>>>(pairs, pbase, cnt, N);
    dinv_kernel<<<(N + 255) / 256, 256, 0, stream>>>(cnt, dinv, N);
    int nb1 = (N + 1023) / 1024;
    scan1_kernel<<<nb1, 256, 0, stream>>>(cnt, offs, bsums, N);
    scan2g_kernel<<<1, 256, 0, stream>>>(bsums, nb1);
    scan3_kernel<<<nb1, 256, 0, stream>>>(offs, bsums, N, E);
    passC_kernel<<<NB, 256, 0, stream>>>(pairs, pbase, offs, csr_src, N);

    // MLP (fused) + hop0
    wconv_kernel<<<(256 * 256 + 255) / 256, 256, 0, stream>>>(W1, W1t, 256, 256);
    wconv_kernel<<<(64 * 256 + 255) / 256, 256, 0, stream>>>(W2, W2t, 256, 64);
    int gb = (N + 127) / 128;
    mlp_fused<<<gb, 256, 0, stream>>>(x, W1t, b1, W2t, b2, dinv, pw, pb,
                                      out, (unsigned short*)gA, N);

    // propagation + fused pooling
    int nwb = (N + 3) / 4;  // 4 waves (=4 dest nodes) per 256-thread block
    __hip_bfloat16* gin = gA;
    __hip_bfloat16* gout = gB;
    for (int k = 0; k < 10; ++k) {
        spmm_kernel<<<nwb, 256, 0, stream>>>(offs, csr_src, dinv, gin, gout, out, pw, pb, N);
        __hip_bfloat16* t = gin; gin = gout; gout = t;
    }
}

// Round 9
// 1111.812 us; speedup vs baseline: 1.3830x; 1.0339x over previous
//
#include <hip/hip_runtime.h>
#include <hip/hip_bf16.h>
#include <math.h>

// DAGNN r9: mlp_fused restructured for occupancy:
//  - BM=64, LDS = xfrag(4KB) + h1frag(33KB) only -> 4 blocks/CU (16 waves/CU)
//  - W1/W2 MFMA B-fragments loaded direct from global (L2-resident), no LDS staging
//  - region-padded LDS layout (stride 520 ushorts) kills the 4-way write conflicts
//  - stage2 + epilogue on waves 0,1
// Build: r7 zero-global-atomic bucket sort. spmm: r3 form (bf16 state).

#define WAVE 64
#define NBLK 1024   // blocks in passA/passB; must match between them
#define RS 520      // LDS region stride in ushorts (64*8 + 8 pad)

__device__ inline float bf2f(unsigned short u) {
    union { unsigned int i; float f; } v; v.i = ((unsigned int)u) << 16; return v.f;
}
__device__ inline unsigned short f2bf(float f) {
    __hip_bfloat16 b = __float2bfloat16(f);
    union { __hip_bfloat16 b; unsigned short u; } v; v.b = b; return v.u;
}

typedef __attribute__((ext_vector_type(8))) short bf16x8;
typedef __attribute__((ext_vector_type(16))) float f32x16;

// ---- edge dtype detection: stride 1 (int32) or 2 (int64 low words) ----
__global__ void detect_kernel(const unsigned* __restrict__ e, int* __restrict__ sflag) {
    __shared__ int any;
    if (threadIdx.x == 0) any = 0;
    __syncthreads();
    unsigned nz = 0;
    int t = threadIdx.x;
    for (int i = 0; i < 8; ++i) nz |= e[(size_t)(t * 8 + i) * 2 + 1];
    if (nz) atomicOr(&any, 1);
    __syncthreads();
    if (t == 0) *sflag = any ? 1 : 2;
}

// ---- passA: per-block LDS bucket histogram (no global atomics) ----
__global__ void passA_kernel(const int* __restrict__ eidx, const int* __restrict__ sflag,
                             int* __restrict__ blk_cnt, int E, int NB, int EPB) {
    __shared__ int lh[512];
    int t = threadIdx.x, blk = blockIdx.x;
    for (int i = t; i < NB; i += 256) lh[i] = 0;
    __syncthreads();
    int s = *sflag;
    int base = blk * EPB;
    int end = base + EPB; if (end > E) end = E;
    for (int e = base + t; e < end; e += 256) {
        int c = eidx[(size_t)s * (size_t)(E + e)];
        atomicAdd(&lh[c >> 8], 1);
    }
    __syncthreads();
    for (int i = t; i < NB; i += 256)
        blk_cnt[(size_t)i * NBLK + blk] = lh[i];
}

// ---- scans ----
__global__ void scan1_kernel(const int* __restrict__ in, int* __restrict__ out,
                             int* __restrict__ bsums, int n) {
    __shared__ int s[256];
    int t = threadIdx.x;
    int idx = blockIdx.x * 1024 + t * 4;
    int x0 = (idx + 0 < n) ? in[idx + 0] : 0;
    int x1 = (idx + 1 < n) ? in[idx + 1] : 0;
    int x2 = (idx + 2 < n) ? in[idx + 2] : 0;
    int x3 = (idx + 3 < n) ? in[idx + 3] : 0;
    int lsum = x0 + x1 + x2 + x3;
    s[t] = lsum;
    __syncthreads();
    for (int o = 1; o < 256; o <<= 1) {
        int v = (t >= o) ? s[t - o] : 0;
        __syncthreads();
        if (t >= o) s[t] += v;
        __syncthreads();
    }
    int excl = s[t] - lsum;
    if (idx + 0 < n) out[idx + 0] = excl;
    if (idx + 1 < n) out[idx + 1] = excl + x0;
    if (idx + 2 < n) out[idx + 2] = excl + x0 + x1;
    if (idx + 3 < n) out[idx + 3] = excl + x0 + x1 + x2;
    if (t == 255) bsums[blockIdx.x] = s[255];
}

__global__ void scan2g_kernel(int* __restrict__ bsums, int nb) {
    __shared__ int part[256];
    int t = threadIdx.x;
    int v[4]; int run = 0;
    #pragma unroll
    for (int j = 0; j < 4; ++j) {
        int i = t * 4 + j;
        int x = (i < nb) ? bsums[i] : 0;
        v[j] = run; run += x;
    }
    part[t] = run;
    __syncthreads();
    for (int o = 1; o < 256; o <<= 1) {
        int x = (t >= o) ? part[t - o] : 0;
        __syncthreads();
        if (t >= o) part[t] += x;
        __syncthreads();
    }
    int excl = part[t] - run;
    #pragma unroll
    for (int j = 0; j < 4; ++j) {
        int i = t * 4 + j;
        if (i < nb) bsums[i] = excl + v[j];
    }
}

__global__ void scan3_kernel(int* __restrict__ arr, const int* __restrict__ bsums,
                             int n, int total) {
    int t = threadIdx.x;
    int idx = blockIdx.x * 1024 + t * 4;
    int add = bsums[blockIdx.x];
    #pragma unroll
    for (int i = 0; i < 4; ++i)
        if (idx + i < n) arr[idx + i] += add;
    if (blockIdx.x == 0 && t == 0) arr[n] = total;
}

// ---- passB: LDS-cursor pair scatter into private (bucket,block) windows ----
__global__ void passB_kernel(const int* __restrict__ eidx, const int* __restrict__ sflag,
                             const int* __restrict__ pbase, int2* __restrict__ pairs,
                             int E, int NB, int EPB) {
    __shared__ int lcur[512];
    int t = threadIdx.x, blk = blockIdx.x;
    for (int i = t; i < NB; i += 256) lcur[i] = pbase[(size_t)i * NBLK + blk];
    __syncthreads();
    int s = *sflag;
    int base = blk * EPB;
    int end = base + EPB; if (end > E) end = E;
    for (int e = base + t; e < end; e += 256) {
        int r = eidx[(size_t)s * (size_t)e];
        int c = eidx[(size_t)s * (size_t)(E + e)];
        int pos = atomicAdd(&lcur[c >> 8], 1);
        pairs[pos] = make_int2(r, c);
    }
}

// ---- passD: per-bucket node degree counts from bucketed pairs ----
__global__ void passD_kernel(const int2* __restrict__ pairs, const int* __restrict__ pbase,
                             int* __restrict__ cnt, int N) {
    __shared__ int lcnt[256];
    int b = blockIdx.x, t = threadIdx.x;
    lcnt[t] = 0;
    __syncthreads();
    int w0 = pbase[(size_t)b * NBLK], w1 = pbase[(size_t)(b + 1) * NBLK];
    for (int i = w0 + t; i < w1; i += 256)
        atomicAdd(&lcnt[pairs[i].y & 255], 1);
    __syncthreads();
    int node = b * 256 + t;
    if (node < N) cnt[node] = lcnt[t];
}

__global__ void dinv_kernel(const int* __restrict__ cnt, float* __restrict__ dinv, int n) {
    int i = blockIdx.x * blockDim.x + threadIdx.x;
    if (i < n) dinv[i] = rsqrtf((float)(cnt[i] + 1));  // self-loop adds 1
}

// ---- passC: per-bucket LDS cursors, scatter src into final CSR window ----
__global__ void passC_kernel(const int2* __restrict__ pairs, const int* __restrict__ pbase,
                             const int* __restrict__ offs, int* __restrict__ csr_src,
                             int N) {
    __shared__ int lcur[256];
    int b = blockIdx.x, t = threadIdx.x;
    int node = b * 256 + t;
    lcur[t] = (node < N) ? offs[node] : 0;
    __syncthreads();
    int w0 = pbase[(size_t)b * NBLK], w1 = pbase[(size_t)(b + 1) * NBLK];
    for (int i = w0 + t; i < w1; i += 256) {
        int2 p = pairs[i];
        int pos = atomicAdd(&lcur[p.y & 255], 1);
        csr_src[pos] = p.x;
    }
}

// ---- weight convert+transpose: Wt[n][k] = bf16(W[k][n]) ----
__global__ void wconv_kernel(const float* __restrict__ W, unsigned short* __restrict__ Wt,
                             int K, int Nn) {
    int i = blockIdx.x * blockDim.x + threadIdx.x;
    if (i >= K * Nn) return;
    int n = i / K, k = i - n * K;
    Wt[(size_t)n * K + k] = f2bf(W[(size_t)k * Nn + n]);
}

// ---- fused MLP: h = relu(x@W1+b1)@W2+b2 ; out = sigmoid(h.pw+pb)*h ;
//      g0 = bf16(dinv*h).  BM=64 rows/block, 256 thr (4 waves).
// LDS: region-padded fragment-major (region stride RS=520 ushorts).
// Weights read direct from global (L2-resident). ----
__global__ __launch_bounds__(256, 4) void mlp_fused(
        const float* __restrict__ x,
        const unsigned short* __restrict__ W1t,   // [256 n][256 k] bf16
        const float* __restrict__ b1,
        const unsigned short* __restrict__ W2t,   // [64 n][256 k] bf16
        const float* __restrict__ b2,
        const float* __restrict__ dinv,
        const float* __restrict__ pw, const float* __restrict__ pb,
        float* __restrict__ out, unsigned short* __restrict__ g,
        int M) {
    __shared__ unsigned short xfrag[4 * RS];    // region = k16*2+half
    __shared__ unsigned short h1frag[32 * RS];  // region = k16*2+half (k of stage2)

    int tid = threadIdx.x;
    int wave = tid >> 6, lane = tid & 63;
    int half = lane >> 5, l31 = lane & 31;
    int rt = wave & 1;          // stage-1 row tile (32 rows)
    int cw = wave >> 1;         // stage-1 col half (128 cols)
    int bm = blockIdx.x * 64;

    f32x16 acc1[4] = {};

    // x staging slots: thread handles f = tid and tid+256 (512 float4 total)
    float4 xv[2];
    #pragma unroll
    for (int i = 0; i < 2; ++i) {
        int f = i * 256 + tid;
        int row = f >> 3, c4 = (f & 7) * 4;
        int grow = bm + row;
        xv[i] = (grow < M) ? *(const float4*)(x + (size_t)grow * 256 + c4)
                           : make_float4(0.f, 0.f, 0.f, 0.f);
    }

    for (int it = 0; it < 8; ++it) {
        // commit prefetched x tile to LDS (bf16, region-padded fragment layout)
        #pragma unroll
        for (int i = 0; i < 2; ++i) {
            int f = i * 256 + tid;
            int row = f >> 3, c4 = (f & 7) * 4;
            int region = c4 >> 3, off = c4 & 7;
            ushort4 u;
            u.x = f2bf(xv[i].x); u.y = f2bf(xv[i].y);
            u.z = f2bf(xv[i].z); u.w = f2bf(xv[i].w);
            *(ushort4*)&xfrag[region * RS + row * 8 + off] = u;
        }
        __syncthreads();
        // prefetch next x tile
        if (it < 7) {
            int k0 = (it + 1) * 32;
            #pragma unroll
            for (int i = 0; i < 2; ++i) {
                int f = i * 256 + tid;
                int row = f >> 3, c4 = (f & 7) * 4;
                int grow = bm + row;
                xv[i] = (grow < M) ? *(const float4*)(x + (size_t)grow * 256 + k0 + c4)
                                   : make_float4(0.f, 0.f, 0.f, 0.f);
            }
        }
        // MFMAs; B fragments direct from global (L2-hot)
        int kg = it * 32 + half * 8;
        #pragma unroll
        for (int s = 0; s < 2; ++s) {
            bf16x8 a = *(bf16x8*)&xfrag[(s * 2 + half) * RS + (rt * 32 + l31) * 8];
            #pragma unroll
            for (int j = 0; j < 4; ++j) {
                int ch = cw * 128 + j * 32 + l31;
                bf16x8 b = *(const bf16x8*)(W1t + (size_t)ch * 256 + kg + s * 16);
                acc1[j] = __builtin_amdgcn_mfma_f32_32x32x16_bf16(a, b, acc1[j], 0, 0, 0);
            }
        }
        __syncthreads();
    }

    // bias + relu, write h1 tile to LDS in stage-2 A-fragment layout
    #pragma unroll
    for (int j = 0; j < 4; ++j) {
        int ch = cw * 128 + j * 32 + l31;     // stage-2 k index
        float bb = b1[ch];
        int region = ch >> 3, off = ch & 7;
        #pragma unroll
        for (int reg = 0; reg < 16; ++reg) {
            int rowin = (reg & 3) + 8 * (reg >> 2) + 4 * half;
            int row = rt * 32 + rowin;
            float v = fmaxf(acc1[j][reg] + bb, 0.f);
            h1frag[region * RS + row * 8 + off] = f2bf(v);
        }
    }
    __syncthreads();

    // stage 2 on waves 0,1: wave owns rows wave*32..+31, both col tiles
    if (wave < 2) {
        f32x16 acc2[2] = {};
        #pragma unroll
        for (int s = 0; s < 16; ++s) {
            bf16x8 a = *(bf16x8*)&h1frag[(s * 2 + half) * RS + (wave * 32 + l31) * 8];
            #pragma unroll
            for (int j = 0; j < 2; ++j) {
                bf16x8 b = *(const bf16x8*)(W2t + (size_t)(j * 32 + l31) * 256 + s * 16 + half * 8);
                acc2[j] = __builtin_amdgcn_mfma_f32_32x32x16_bf16(a, b, acc2[j], 0, 0, 0);
            }
        }
        // epilogue: bias, pooling (butterfly over l31), out + g0
        float bb0 = b2[l31], bb1 = b2[32 + l31];
        float pw0 = pw[l31], pw1 = pw[32 + l31];
        float pbv = pb[0];
        #pragma unroll
        for (int reg = 0; reg < 16; ++reg) {
            int rowin = (reg & 3) + 8 * (reg >> 2) + 4 * half;
            int row = bm + wave * 32 + rowin;
            float h0 = acc2[0][reg] + bb0;
            float h1v = acc2[1][reg] + bb1;
            float d = h0 * pw0 + h1v * pw1;
            d += __shfl_xor(d, 1, 64);
            d += __shfl_xor(d, 2, 64);
            d += __shfl_xor(d, 4, 64);
            d += __shfl_xor(d, 8, 64);
            d += __shfl_xor(d, 16, 64);
            float sg = 1.f / (1.f + __expf(-(d + pbv)));
            if (row < M) {
                float dv = dinv[row];
                out[(size_t)row * 64 + l31]      = sg * h0;
                out[(size_t)row * 64 + 32 + l31] = sg * h1v;
                g[(size_t)row * 64 + l31]        = f2bf(dv * h0);
                g[(size_t)row * 64 + 32 + l31]   = f2bf(dv * h1v);
            }
        }
    }
}

// ---- one hop (r3 form): wave per dest, uniform edge indices, bf16 gathers ----
__global__ void spmm_kernel(const int* __restrict__ offs, const int* __restrict__ src,
                            const float* __restrict__ dinv,
                            const __hip_bfloat16* __restrict__ gin,
                            __hip_bfloat16* __restrict__ gout,
                            float* __restrict__ out,
                            const float* __restrict__ pw, const float* __restrict__ pb,
                            int n) {
    int wid = (blockIdx.x * blockDim.x + threadIdx.x) >> 6;
    int lane = threadIdx.x & 63;
    if (wid >= n) return;
    int c = __builtin_amdgcn_readfirstlane(wid);
    int e = __builtin_amdgcn_readfirstlane(offs[c]);
    int eend = __builtin_amdgcn_readfirstlane(offs[c + 1]);
    float acc = 0.f;
    while (e < eend && (e & 3)) {
        acc += __bfloat162float(gin[(size_t)src[e] * 64 + lane]);
        ++e;
    }
    for (; e + 7 < eend; e += 8) {
        int4 sa = *(const int4*)(src + e);
        int4 sb = *(const int4*)(src + e + 4);
        float v0 = __bfloat162float(gin[(size_t)sa.x * 64 + lane]);
        float v1 = __bfloat162float(gin[(size_t)sa.y * 64 + lane]);
        float v2 = __bfloat162float(gin[(size_t)sa.z * 64 + lane]);
        float v3 = __bfloat162float(gin[(size_t)sa.w * 64 + lane]);
        float v4 = __bfloat162float(gin[(size_t)sb.x * 64 + lane]);
        float v5 = __bfloat162float(gin[(size_t)sb.y * 64 + lane]);
        float v6 = __bfloat162float(gin[(size_t)sb.z * 64 + lane]);
        float v7 = __bfloat162float(gin[(size_t)sb.w * 64 + lane]);
        acc += ((v0 + v1) + (v2 + v3)) + ((v4 + v5) + (v6 + v7));
    }
    for (; e + 3 < eend; e += 4) {
        int4 sa = *(const int4*)(src + e);
        float v0 = __bfloat162float(gin[(size_t)sa.x * 64 + lane]);
        float v1 = __bfloat162float(gin[(size_t)sa.y * 64 + lane]);
        float v2 = __bfloat162float(gin[(size_t)sa.z * 64 + lane]);
        float v3 = __bfloat162float(gin[(size_t)sa.w * 64 + lane]);
        acc += (v0 + v1) + (v2 + v3);
    }
    for (; e < eend; ++e) acc += __bfloat162float(gin[(size_t)src[e] * 64 + lane]);

    float dc = dinv[c];
    float h = dc * (acc + __bfloat162float(gin[(size_t)c * 64 + lane]));
    gout[(size_t)c * 64 + lane] = __float2bfloat16(dc * h);
    float d = h * pw[lane];
    #pragma unroll
    for (int o = 32; o > 0; o >>= 1) d += __shfl_xor(d, o, 64);
    float sg = 1.f / (1.f + __expf(-(d + pb[0])));
    out[(size_t)c * 64 + lane] += sg * h;
}

extern "C" void kernel_launch(void* const* d_in, const int* in_sizes, int n_in,
                              void* d_out, int out_size, void* d_ws, size_t ws_size,
                              hipStream_t stream) {
    const float* x  = (const float*)d_in[0];
    const int* eidx = (const int*)d_in[1];
    const float* W1 = (const float*)d_in[2];
    const float* b1 = (const float*)d_in[3];
    const float* W2 = (const float*)d_in[4];
    const float* b2 = (const float*)d_in[5];
    const float* pw = (const float*)d_in[6];
    const float* pb = (const float*)d_in[7];
    float* out = (float*)d_out;

    const int N = in_sizes[0] / 256;
    const int E = in_sizes[1] / 2;
    const int NB = (N + 255) >> 8;              // buckets of 256 dest nodes
    const int EPB = (E + NBLK - 1) / NBLK;      // edges per passA/passB block
    const int M = NB * NBLK;                    // blk_cnt entries

    size_t woff = 0;
    auto alloc = [&](size_t bytes) -> void* {
        void* p = (char*)d_ws + woff;
        woff += (bytes + 255) & ~(size_t)255;
        return p;
    };
    int*   sflag   = (int*)alloc(4);
    int*   cnt     = (int*)alloc((size_t)N * 4);
    float* dinv    = (float*)alloc((size_t)N * 4);
    int*   offs    = (int*)alloc(((size_t)N + 1) * 4);
    int*   bsums   = (int*)alloc(1024 * 4);
    int*   bsums2  = (int*)alloc(1024 * 4);
    int*   pbase   = (int*)alloc(((size_t)M + 1) * 4);
    int*   csr_src = (int*)alloc((size_t)E * 4);
    int2*  pairs   = (int2*)alloc((size_t)E * 8);
    unsigned short* W1t = (unsigned short*)alloc((size_t)256 * 256 * 2);
    unsigned short* W2t = (unsigned short*)alloc((size_t)64 * 256 * 2);
    __hip_bfloat16* gA = (__hip_bfloat16*)alloc((size_t)N * 64 * 2);
    __hip_bfloat16* gB = (__hip_bfloat16*)alloc((size_t)N * 64 * 2);

    detect_kernel<<<1, 256, 0, stream>>>((const unsigned*)eidx, sflag);

    // build: histogram -> scan -> pair scatter -> node counts -> offs -> CSR
    passA_kernel<<<NBLK, 256, 0, stream>>>(eidx, sflag, pbase, E, NB, EPB);
    int nb2 = (M + 1023) / 1024;
    scan1_kernel<<<nb2, 256, 0, stream>>>(pbase, pbase, bsums2, M);
    scan2g_kernel<<<1, 256, 0, stream>>>(bsums2, nb2);
    scan3_kernel<<<nb2, 256, 0, stream>>>(pbase, bsums2, M, E);
    passB_kernel<<<NBLK, 256, 0, stream>>>(eidx, sflag, pbase, pairs, E, NB, EPB);
    passD_kernel<<<NB, 256, 0, stream>>>(pairs, pbase, cnt, N);
    dinv_kernel<<<(N + 255) / 256, 256, 0, stream>>>(cnt, dinv, N);
    int nb1 = (N + 1023) / 1024;
    scan1_kernel<<<nb1, 256, 0, stream>>>(cnt, offs, bsums, N);
    scan2g_kernel<<<1, 256, 0, stream>>>(bsums, nb1);
    scan3_kernel<<<nb1, 256, 0, stream>>>(offs, bsums, N, E);
    passC_kernel<<<NB, 256, 0, stream>>>(pairs, pbase, offs, csr_src, N);

    // MLP (fused) + hop0
    wconv_kernel<<<(256 * 256 + 255) / 256, 256, 0, stream>>>(W1, W1t, 256, 256);
    wconv_kernel<<<(64 * 256 + 255) / 256, 256, 0, stream>>>(W2, W2t, 256, 64);
    int gb = (N + 63) / 64;
    mlp_fused<<<gb, 256, 0, stream>>>(x, W1t, b1, W2t, b2, dinv, pw, pb,
                                      out, (unsigned short*)gA, N);

    // propagation + fused pooling
    int nwb = (N + 3) / 4;  // 4 waves (=4 dest nodes) per 256-thread block
    __hip_bfloat16* gin = gA;
    __hip_bfloat16* gout = gB;
    for (int k = 0; k < 10; ++k) {
        spmm_kernel<<<nwb, 256, 0, stream>>>(offs, csr_src, dinv, gin, gout, out, pw, pb, N);
        __hip_bfloat16* t = gin; gin = gout; gout = t;
    }
}

// Round 10
// 1099.889 us; speedup vs baseline: 1.3980x; 1.0108x over previous
//
#include <hip/hip_runtime.h>
#include <hip/hip_bf16.h>
#include <math.h>

// DAGNN r10:
//  - weights pre-swizzled to fragment-major in GLOBAL (Wf[k>>3][n][k&7]) ->
//    MFMA B-fragment loads are 16B/lane fully coalesced (r9's 512B-stride bug fixed)
//  - mlp stage2 on all 4 waves (2x2 tiles), pooling via 1KB LDS pool reduce
//  - passB pair windows block-major (dense per-block writes, no false sharing)
// Build: zero-global-atomic bucket sort. spmm: r3 form (bf16 state).

#define WAVE 64
#define NBLK 1024   // blocks in passA/passB; must match between them
#define RS 520      // LDS region stride in ushorts (64*8 + 8 pad)

__device__ inline float bf2f(unsigned short u) {
    union { unsigned int i; float f; } v; v.i = ((unsigned int)u) << 16; return v.f;
}
__device__ inline unsigned short f2bf(float f) {
    __hip_bfloat16 b = __float2bfloat16(f);
    union { __hip_bfloat16 b; unsigned short u; } v; v.b = b; return v.u;
}

typedef __attribute__((ext_vector_type(8))) short bf16x8;
typedef __attribute__((ext_vector_type(16))) float f32x16;

// ---- edge dtype detection: stride 1 (int32) or 2 (int64 low words) ----
__global__ void detect_kernel(const unsigned* __restrict__ e, int* __restrict__ sflag) {
    __shared__ int any;
    if (threadIdx.x == 0) any = 0;
    __syncthreads();
    unsigned nz = 0;
    int t = threadIdx.x;
    for (int i = 0; i < 8; ++i) nz |= e[(size_t)(t * 8 + i) * 2 + 1];
    if (nz) atomicOr(&any, 1);
    __syncthreads();
    if (t == 0) *sflag = any ? 1 : 2;
}

// ---- passA: per-block LDS bucket histogram; blk_cnt[blk][bucket] ----
__global__ void passA_kernel(const int* __restrict__ eidx, const int* __restrict__ sflag,
                             int* __restrict__ blk_cnt, int E, int NB, int EPB) {
    __shared__ int lh[512];
    int t = threadIdx.x, blk = blockIdx.x;
    for (int i = t; i < NB; i += 256) lh[i] = 0;
    __syncthreads();
    int s = *sflag;
    int base = blk * EPB;
    int end = base + EPB; if (end > E) end = E;
    for (int e = base + t; e < end; e += 256) {
        int c = eidx[(size_t)s * (size_t)(E + e)];
        atomicAdd(&lh[c >> 8], 1);
    }
    __syncthreads();
    for (int i = t; i < NB; i += 256)
        blk_cnt[(size_t)blk * NB + i] = lh[i];
}

// ---- scans ----
__global__ void scan1_kernel(const int* __restrict__ in, int* __restrict__ out,
                             int* __restrict__ bsums, int n) {
    __shared__ int s[256];
    int t = threadIdx.x;
    int idx = blockIdx.x * 1024 + t * 4;
    int x0 = (idx + 0 < n) ? in[idx + 0] : 0;
    int x1 = (idx + 1 < n) ? in[idx + 1] : 0;
    int x2 = (idx + 2 < n) ? in[idx + 2] : 0;
    int x3 = (idx + 3 < n) ? in[idx + 3] : 0;
    int lsum = x0 + x1 + x2 + x3;
    s[t] = lsum;
    __syncthreads();
    for (int o = 1; o < 256; o <<= 1) {
        int v = (t >= o) ? s[t - o] : 0;
        __syncthreads();
        if (t >= o) s[t] += v;
        __syncthreads();
    }
    int excl = s[t] - lsum;
    if (idx + 0 < n) out[idx + 0] = excl;
    if (idx + 1 < n) out[idx + 1] = excl + x0;
    if (idx + 2 < n) out[idx + 2] = excl + x0 + x1;
    if (idx + 3 < n) out[idx + 3] = excl + x0 + x1 + x2;
    if (t == 255) bsums[blockIdx.x] = s[255];
}

__global__ void scan2g_kernel(int* __restrict__ bsums, int nb) {
    __shared__ int part[256];
    int t = threadIdx.x;
    int v[4]; int run = 0;
    #pragma unroll
    for (int j = 0; j < 4; ++j) {
        int i = t * 4 + j;
        int x = (i < nb) ? bsums[i] : 0;
        v[j] = run; run += x;
    }
    part[t] = run;
    __syncthreads();
    for (int o = 1; o < 256; o <<= 1) {
        int x = (t >= o) ? part[t - o] : 0;
        __syncthreads();
        if (t >= o) part[t] += x;
        __syncthreads();
    }
    int excl = part[t] - run;
    #pragma unroll
    for (int j = 0; j < 4; ++j) {
        int i = t * 4 + j;
        if (i < nb) bsums[i] = excl + v[j];
    }
}

__global__ void scan3_kernel(int* __restrict__ arr, const int* __restrict__ bsums,
                             int n, int total) {
    int t = threadIdx.x;
    int idx = blockIdx.x * 1024 + t * 4;
    int add = bsums[blockIdx.x];
    #pragma unroll
    for (int i = 0; i < 4; ++i)
        if (idx + i < n) arr[idx + i] += add;
    if (blockIdx.x == 0 && t == 0) arr[n] = total;
}

// ---- passB: LDS-cursor pair scatter; windows block-major (dense per block) ----
__global__ void passB_kernel(const int* __restrict__ eidx, const int* __restrict__ sflag,
                             const int* __restrict__ pbase, int2* __restrict__ pairs,
                             int E, int NB, int EPB) {
    __shared__ int lcur[512];
    int t = threadIdx.x, blk = blockIdx.x;
    for (int i = t; i < NB; i += 256) lcur[i] = pbase[(size_t)blk * NB + i];
    __syncthreads();
    int s = *sflag;
    int base = blk * EPB;
    int end = base + EPB; if (end > E) end = E;
    for (int e = base + t; e < end; e += 256) {
        int r = eidx[(size_t)s * (size_t)e];
        int c = eidx[(size_t)s * (size_t)(E + e)];
        int pos = atomicAdd(&lcur[c >> 8], 1);
        pairs[pos] = make_int2(r, c);
    }
}

// ---- passD: per-bucket node degree counts; windows at pbase[blk*NB+b] ----
__global__ void passD_kernel(const int2* __restrict__ pairs, const int* __restrict__ pbase,
                             int* __restrict__ cnt, int N, int NB) {
    __shared__ int lcnt[256];
    int b = blockIdx.x, t = threadIdx.x;
    lcnt[t] = 0;
    __syncthreads();
    for (int blk = t; blk < NBLK; blk += 256) {
        int w0 = pbase[(size_t)blk * NB + b];
        int w1 = pbase[(size_t)blk * NB + b + 1];
        for (int i = w0; i < w1; ++i)
            atomicAdd(&lcnt[pairs[i].y & 255], 1);
    }
    __syncthreads();
    int node = b * 256 + t;
    if (node < N) cnt[node] = lcnt[t];
}

__global__ void dinv_kernel(const int* __restrict__ cnt, float* __restrict__ dinv, int n) {
    int i = blockIdx.x * blockDim.x + threadIdx.x;
    if (i < n) dinv[i] = rsqrtf((float)(cnt[i] + 1));  // self-loop adds 1
}

// ---- passC: per-bucket LDS cursors, scatter src into final CSR window ----
__global__ void passC_kernel(const int2* __restrict__ pairs, const int* __restrict__ pbase,
                             const int* __restrict__ offs, int* __restrict__ csr_src,
                             int N, int NB) {
    __shared__ int lcur[256];
    int b = blockIdx.x, t = threadIdx.x;
    int node = b * 256 + t;
    lcur[t] = (node < N) ? offs[node] : 0;
    __syncthreads();
    for (int blk = t; blk < NBLK; blk += 256) {
        int w0 = pbase[(size_t)blk * NB + b];
        int w1 = pbase[(size_t)blk * NB + b + 1];
        for (int i = w0; i < w1; ++i) {
            int2 p = pairs[i];
            int pos = atomicAdd(&lcur[p.y & 255], 1);
            csr_src[pos] = p.x;
        }
    }
}

// ---- weight convert to fragment-major: Wf[(k>>3)*Nn*8 + n*8 + (k&7)] = bf16(W[k][n]) ----
__global__ void wconv_kernel(const float* __restrict__ W, unsigned short* __restrict__ Wf,
                             int K, int Nn) {
    int i = blockIdx.x * blockDim.x + threadIdx.x;
    if (i >= K * Nn) return;
    int k = i / Nn, n = i - k * Nn;
    Wf[(size_t)(k >> 3) * Nn * 8 + n * 8 + (k & 7)] = f2bf(W[i]);
}

// ---- fused MLP: h = relu(x@W1+b1)@W2+b2 ; out = sigmoid(h.pw+pb)*h ;
//      g0 = bf16(dinv*h).  BM=64 rows/block, 256 thr (4 waves).
// Weights fragment-major in global (coalesced 16B/lane B-loads). ----
__global__ __launch_bounds__(256, 4) void mlp_fused(
        const float* __restrict__ x,
        const unsigned short* __restrict__ W1f,   // frag-major [k>>3][256 n][8]
        const float* __restrict__ b1,
        const unsigned short* __restrict__ W2f,   // frag-major [k>>3][64 n][8]
        const float* __restrict__ b2,
        const float* __restrict__ dinv,
        const float* __restrict__ pw, const float* __restrict__ pb,
        float* __restrict__ out, unsigned short* __restrict__ g,
        int M) {
    __shared__ unsigned short xfrag[4 * RS];    // region = (k&31)>>3
    __shared__ unsigned short h1frag[32 * RS];  // region = ch>>3 (stage-2 k)
    __shared__ float pools[2][2][2][16];        // [rt2][ct2][half][reg]

    int tid = threadIdx.x;
    int wave = tid >> 6, lane = tid & 63;
    int half = lane >> 5, l31 = lane & 31;
    int rt = wave & 1;          // stage-1 row tile (32 rows)
    int cw = wave >> 1;         // stage-1 col half (128 cols)
    int bm = blockIdx.x * 64;

    f32x16 acc1[4] = {};

    float4 xv[2];
    #pragma unroll
    for (int i = 0; i < 2; ++i) {
        int f = i * 256 + tid;
        int row = f >> 3, c4 = (f & 7) * 4;
        int grow = bm + row;
        xv[i] = (grow < M) ? *(const float4*)(x + (size_t)grow * 256 + c4)
                           : make_float4(0.f, 0.f, 0.f, 0.f);
    }

    for (int it = 0; it < 8; ++it) {
        #pragma unroll
        for (int i = 0; i < 2; ++i) {
            int f = i * 256 + tid;
            int row = f >> 3, c4 = (f & 7) * 4;
            int region = c4 >> 3, off = c4 & 7;
            ushort4 u;
            u.x = f2bf(xv[i].x); u.y = f2bf(xv[i].y);
            u.z = f2bf(xv[i].z); u.w = f2bf(xv[i].w);
            *(ushort4*)&xfrag[region * RS + row * 8 + off] = u;
        }
        __syncthreads();
        if (it < 7) {
            int k0 = (it + 1) * 32;
            #pragma unroll
            for (int i = 0; i < 2; ++i) {
                int f = i * 256 + tid;
                int row = f >> 3, c4 = (f & 7) * 4;
                int grow = bm + row;
                xv[i] = (grow < M) ? *(const float4*)(x + (size_t)grow * 256 + k0 + c4)
                                   : make_float4(0.f, 0.f, 0.f, 0.f);
            }
        }
        // MFMAs; B fragments coalesced from global frag-major layout
        #pragma unroll
        for (int s = 0; s < 2; ++s) {
            int region = it * 4 + s * 2 + half;          // k>>3 of this fragment
            bf16x8 a = *(bf16x8*)&xfrag[(s * 2 + half) * RS + (rt * 32 + l31) * 8];
            #pragma unroll
            for (int j = 0; j < 4; ++j) {
                int ch = cw * 128 + j * 32 + l31;
                bf16x8 b = *(const bf16x8*)(W1f + (size_t)region * 2048 + ch * 8);
                acc1[j] = __builtin_amdgcn_mfma_f32_32x32x16_bf16(a, b, acc1[j], 0, 0, 0);
            }
        }
        __syncthreads();
    }

    // bias + relu, write h1 tile to LDS in stage-2 A-fragment layout
    #pragma unroll
    for (int j = 0; j < 4; ++j) {
        int ch = cw * 128 + j * 32 + l31;     // stage-2 k index
        float bb = b1[ch];
        int region = ch >> 3, off = ch & 7;
        #pragma unroll
        for (int reg = 0; reg < 16; ++reg) {
            int rowin = (reg & 3) + 8 * (reg >> 2) + 4 * half;
            int row = rt * 32 + rowin;
            float v = fmaxf(acc1[j][reg] + bb, 0.f);
            h1frag[region * RS + row * 8 + off] = f2bf(v);
        }
    }
    __syncthreads();

    // stage 2 on all 4 waves: wave = rt2*2 + ct2 tile (32 rows x 32 cols)
    int rt2 = wave >> 1, ct2 = wave & 1;
    f32x16 acc2 = {};
    #pragma unroll
    for (int s = 0; s < 16; ++s) {
        bf16x8 a = *(bf16x8*)&h1frag[(s * 2 + half) * RS + (rt2 * 32 + l31) * 8];
        bf16x8 b = *(const bf16x8*)(W2f + (size_t)(s * 2 + half) * 512 + (ct2 * 32 + l31) * 8);
        acc2 = __builtin_amdgcn_mfma_f32_32x32x16_bf16(a, b, acc2, 0, 0, 0);
    }

    // pooling partials: butterfly over 32 cols, pool-exchange across col tiles
    float bb = b2[ct2 * 32 + l31];
    float pwv = pw[ct2 * 32 + l31];
    float pbv = pb[0];
    float hreg[16];
    #pragma unroll
    for (int reg = 0; reg < 16; ++reg) {
        float h = acc2[reg] + bb;
        hreg[reg] = h;
        float d = h * pwv;
        d += __shfl_xor(d, 1, 64);
        d += __shfl_xor(d, 2, 64);
        d += __shfl_xor(d, 4, 64);
        d += __shfl_xor(d, 8, 64);
        d += __shfl_xor(d, 16, 64);
        if (l31 == 0) pools[rt2][ct2][half][reg] = d;
    }
    __syncthreads();
    #pragma unroll
    for (int reg = 0; reg < 16; ++reg) {
        int rowin = (reg & 3) + 8 * (reg >> 2) + 4 * half;
        int row = bm + rt2 * 32 + rowin;
        float d = pools[rt2][0][half][reg] + pools[rt2][1][half][reg];
        float sg = 1.f / (1.f + __expf(-(d + pbv)));
        float h = hreg[reg];
        if (row < M) {
            float dv = dinv[row];
            out[(size_t)row * 64 + ct2 * 32 + l31] = sg * h;
            g[(size_t)row * 64 + ct2 * 32 + l31]   = f2bf(dv * h);
        }
    }
}

// ---- one hop (r3 form): wave per dest, uniform edge indices, bf16 gathers ----
__global__ void spmm_kernel(const int* __restrict__ offs, const int* __restrict__ src,
                            const float* __restrict__ dinv,
                            const __hip_bfloat16* __restrict__ gin,
                            __hip_bfloat16* __restrict__ gout,
                            float* __restrict__ out,
                            const float* __restrict__ pw, const float* __restrict__ pb,
                            int n) {
    int wid = (blockIdx.x * blockDim.x + threadIdx.x) >> 6;
    int lane = threadIdx.x & 63;
    if (wid >= n) return;
    int c = __builtin_amdgcn_readfirstlane(wid);
    int e = __builtin_amdgcn_readfirstlane(offs[c]);
    int eend = __builtin_amdgcn_readfirstlane(offs[c + 1]);
    float acc = 0.f;
    while (e < eend && (e & 3)) {
        acc += __bfloat162float(gin[(size_t)src[e] * 64 + lane]);
        ++e;
    }
    for (; e + 7 < eend; e += 8) {
        int4 sa = *(const int4*)(src + e);
        int4 sb = *(const int4*)(src + e + 4);
        float v0 = __bfloat162float(gin[(size_t)sa.x * 64 + lane]);
        float v1 = __bfloat162float(gin[(size_t)sa.y * 64 + lane]);
        float v2 = __bfloat162float(gin[(size_t)sa.z * 64 + lane]);
        float v3 = __bfloat162float(gin[(size_t)sa.w * 64 + lane]);
        float v4 = __bfloat162float(gin[(size_t)sb.x * 64 + lane]);
        float v5 = __bfloat162float(gin[(size_t)sb.y * 64 + lane]);
        float v6 = __bfloat162float(gin[(size_t)sb.z * 64 + lane]);
        float v7 = __bfloat162float(gin[(size_t)sb.w * 64 + lane]);
        acc += ((v0 + v1) + (v2 + v3)) + ((v4 + v5) + (v6 + v7));
    }
    for (; e + 3 < eend; e += 4) {
        int4 sa = *(const int4*)(src + e);
        float v0 = __bfloat162float(gin[(size_t)sa.x * 64 + lane]);
        float v1 = __bfloat162float(gin[(size_t)sa.y * 64 + lane]);
        float v2 = __bfloat162float(gin[(size_t)sa.z * 64 + lane]);
        float v3 = __bfloat162float(gin[(size_t)sa.w * 64 + lane]);
        acc += (v0 + v1) + (v2 + v3);
    }
    for (; e < eend; ++e) acc += __bfloat162float(gin[(size_t)src[e] * 64 + lane]);

    float dc = dinv[c];
    float h = dc * (acc + __bfloat162float(gin[(size_t)c * 64 + lane]));
    gout[(size_t)c * 64 + lane] = __float2bfloat16(dc * h);
    float d = h * pw[lane];
    #pragma unroll
    for (int o = 32; o > 0; o >>= 1) d += __shfl_xor(d, o, 64);
    float sg = 1.f / (1.f + __expf(-(d + pb[0])));
    out[(size_t)c * 64 + lane] += sg * h;
}

extern "C" void kernel_launch(void* const* d_in, const int* in_sizes, int n_in,
                              void* d_out, int out_size, void* d_ws, size_t ws_size,
                              hipStream_t stream) {
    const float* x  = (const float*)d_in[0];
    const int* eidx = (const int*)d_in[1];
    const float* W1 = (const float*)d_in[2];
    const float* b1 = (const float*)d_in[3];
    const float* W2 = (const float*)d_in[4];
    const float* b2 = (const float*)d_in[5];
    const float* pw = (const float*)d_in[6];
    const float* pb = (const float*)d_in[7];
    float* out = (float*)d_out;

    const int N = in_sizes[0] / 256;
    const int E = in_sizes[1] / 2;
    const int NB = (N + 255) >> 8;              // buckets of 256 dest nodes
    const int EPB = (E + NBLK - 1) / NBLK;      // edges per passA/passB block
    const int M = NB * NBLK;                    // blk_cnt entries

    size_t woff = 0;
    auto alloc = [&](size_t bytes) -> void* {
        void* p = (char*)d_ws + woff;
        woff += (bytes + 255) & ~(size_t)255;
        return p;
    };
    int*   sflag   = (int*)alloc(4);
    int*   cnt     = (int*)alloc((size_t)N * 4);
    float* dinv    = (float*)alloc((size_t)N * 4);
    int*   offs    = (int*)alloc(((size_t)N + 1) * 4);
    int*   bsums   = (int*)alloc(1024 * 4);
    int*   bsums2  = (int*)alloc(1024 * 4);
    int*   pbase   = (int*)alloc(((size_t)M + 1) * 4);
    int*   csr_src = (int*)alloc((size_t)E * 4);
    int2*  pairs   = (int2*)alloc((size_t)E * 8);
    unsigned short* W1f = (unsigned short*)alloc((size_t)256 * 256 * 2);
    unsigned short* W2f = (unsigned short*)alloc((size_t)64 * 256 * 2);
    __hip_bfloat16* gA = (__hip_bfloat16*)alloc((size_t)N * 64 * 2);
    __hip_bfloat16* gB = (__hip_bfloat16*)alloc((size_t)N * 64 * 2);

    detect_kernel<<<1, 256, 0, stream>>>((const unsigned*)eidx, sflag);

    // build: histogram -> scan -> pair scatter -> node counts -> offs -> CSR
    passA_kernel<<<NBLK, 256, 0, stream>>>(eidx, sflag, pbase, E, NB, EPB);
    int nb2 = (M + 1023) / 1024;
    scan1_kernel<<<nb2, 256, 0, stream>>>(pbase, pbase, bsums2, M);
    scan2g_kernel<<<1, 256, 0, stream>>>(bsums2, nb2);
    scan3_kernel<<<nb2, 256, 0, stream>>>(pbase, bsums2, M, E);
    passB_kernel<<<NBLK, 256, 0, stream>>>(eidx, sflag, pbase, pairs, E, NB, EPB);
    passD_kernel<<<NB, 256, 0, stream>>>(pairs, pbase, cnt, N, NB);
    dinv_kernel<<<(N + 255) / 256, 256, 0, stream>>>(cnt, dinv, N);
    int nb1 = (N + 1023) / 1024;
    scan1_kernel<<<nb1, 256, 0, stream>>>(cnt, offs, bsums, N);
    scan2g_kernel<<<1, 256, 0, stream>>>(bsums, nb1);
    scan3_kernel<<<nb1, 256, 0, stream>>>(offs, bsums, N, E);
    passC_kernel<<<NB, 256, 0, stream>>>(pairs, pbase, offs, csr_src, N, NB);

    // MLP (fused) + hop0
    wconv_kernel<<<(256 * 256 + 255) / 256, 256, 0, stream>>>(W1, W1f, 256, 256);
    wconv_kernel<<<(64 * 256 + 255) / 256, 256, 0, stream>>>(W2, W2f, 256, 64);
    int gb = (N + 63) / 64;
    mlp_fused<<<gb, 256, 0, stream>>>(x, W1f, b1, W2f, b2, dinv, pw, pb,
                                      out, (unsigned short*)gA, N);

    // propagation + fused pooling
    int nwb = (N + 3) / 4;  // 4 waves (=4 dest nodes) per 256-thread block
    __hip_bfloat16* gin = gA;
    __hip_bfloat16* gout = gB;
    for (int k = 0; k < 10; ++k) {
        spmm_kernel<<<nwb, 256, 0, stream>>>(offs, csr_src, dinv, gin, gout, out, pw, pb, N);
        __hip_bfloat16* t = gin; gin = gout; gout = t;
    }
}